// Round 6
// baseline (879.042 us; speedup 1.0000x reference)
//
#include <hip/hip_runtime.h>

#define HID 128   // feature width (D == H == 128)

// ---------------- bf16 helpers ----------------
__device__ __forceinline__ float bf2f(unsigned short u) {
    union { unsigned int i; float f; } v;
    v.i = ((unsigned int)u) << 16;
    return v.f;
}
__device__ __forceinline__ unsigned short f2bf(float f) {
    union { float f; unsigned int i; } v;
    v.f = f;
    unsigned int lsb = (v.i >> 16) & 1u;
    v.i += 0x7fffu + lsb;   // round-to-nearest-even
    return (unsigned short)(v.i >> 16);
}

typedef __attribute__((ext_vector_type(8))) short bf16x8;   // 8 bf16 (4 VGPRs)
typedef __attribute__((ext_vector_type(4))) float f32x4;    // MFMA acc

// ---------------- merged preprocessing: deg + wprep + gbounds ---------------
// Independent passes over inputs -> one kernel, block-range dispatch.
__global__ void k_prep(const int* __restrict__ col, int* __restrict__ degI,
                       const float* __restrict__ W1, const float* __restrict__ W2,
                       const float* __restrict__ W3, const float* __restrict__ W4,
                       unsigned short* __restrict__ Wg,
                       const int* __restrict__ batch, int* __restrict__ gstart,
                       int E, int N, int G, int degGrid) {
    int bid = blockIdx.x;
    if (bid < degGrid) {                       // ---- degree histogram ----
        int i = bid * 256 + threadIdx.x;
        if (i < E) atomicAdd(&degI[col[i]], 1);
        return;
    }
    bid -= degGrid;
    if (bid < 256) {                           // ---- W pre-swizzle ----
        int m = bid >> 6;                      // matrix index 0..3
        int i = (bid & 63) * 256 + threadIdx.x;
        const float* Wm = (m == 0) ? W1 : (m == 1) ? W2 : (m == 2) ? W3 : W4;
        int k = i >> 7, n = i & 127;
        int ks = k >> 5, q = (k >> 3) & 3, j = k & 7;
        int ct = n >> 4, c = n & 15;
        Wg[m * 16384 + ((((ks * 8 + ct) * 4 + q) * 16 + c) << 3) + j] = f2bf(Wm[i]);
        return;
    }
    bid -= 256;                                // ---- graph bounds ----
    int g = bid * 256 + threadIdx.x;
    if (g > G) return;
    int lo = 0, hi = N;
    while (lo < hi) {
        int mid = (lo + hi) >> 1;
        if (batch[mid] < g) lo = mid + 1; else hi = mid;
    }
    gstart[g] = lo;
}

// ---- 3-phase device-wide exclusive scan of (degI[i]+1) -> indptr, cursor ----
__global__ void k_scan_part(const int* __restrict__ degI, int* __restrict__ partial,
                            int* __restrict__ sums, int N) {
    __shared__ int sh[1024];
    int tid = threadIdx.x;
    int i = blockIdx.x * 1024 + tid;
    int v = (i < N) ? (degI[i] + 1) : 0;
    sh[tid] = v;
    __syncthreads();
    for (int off = 1; off < 1024; off <<= 1) {
        int t = (tid >= off) ? sh[tid - off] : 0;
        __syncthreads();
        sh[tid] += t;
        __syncthreads();
    }
    if (i < N) partial[i] = sh[tid] - v;
    if (tid == 1023) sums[blockIdx.x] = sh[1023];
}
__global__ void k_scan_tops(int* __restrict__ sums, int* __restrict__ indptr,
                            int nblocks, int N) {
    __shared__ int sh[1024];
    int tid = threadIdx.x;
    int v = (tid < nblocks) ? sums[tid] : 0;
    sh[tid] = v;
    __syncthreads();
    for (int off = 1; off < 1024; off <<= 1) {
        int t = (tid >= off) ? sh[tid - off] : 0;
        __syncthreads();
        sh[tid] += t;
        __syncthreads();
    }
    if (tid < nblocks) sums[tid] = sh[tid] - v;   // exclusive
    if (tid == 1023) indptr[N] = sh[1023];        // grand total = E + N
}
// phase 3: emit indptr + cursor + dinv = 1/sqrt(deg+1)
__global__ void k_scan_fix(const int* __restrict__ partial, const int* __restrict__ sums,
                           const int* __restrict__ degI, int* __restrict__ indptr,
                           int* __restrict__ cursor, float* __restrict__ dinv, int N) {
    int i = blockIdx.x * blockDim.x + threadIdx.x;
    if (i < N) {
        int ex = partial[i] + sums[i >> 10];
        indptr[i] = ex;
        cursor[i] = ex;
        dinv[i] = 1.0f / sqrtf((float)(degI[i] + 1));
    }
}

// ---------------- MFMA GEMM body (C = A @ W, bf16 out, unscaled) -------------
__device__ __forceinline__ bf16x8 a_frag_load(const unsigned short* p) {
    return *(const bf16x8*)p;
}
__device__ __forceinline__ bf16x8 a_frag_load(const float* p) {
    bf16x8 r;
#pragma unroll
    for (int i = 0; i < 8; ++i) r[i] = (short)f2bf(p[i]);
    return r;
}

template <typename TA>
__device__ __forceinline__ void gemm_body(const TA* __restrict__ A,
                                          const unsigned short* __restrict__ B,
                                          unsigned short* __restrict__ C,
                                          int N, int blk) {
    const int tid = threadIdx.x;
    const int lane = tid & 63, wave = tid >> 6;
    const int q = lane >> 4, c = lane & 15;
    const int rowBase = blk * 128 + wave * 32;

    f32x4 acc[2][8];
#pragma unroll
    for (int rt = 0; rt < 2; ++rt)
#pragma unroll
        for (int ct = 0; ct < 8; ++ct)
            acc[rt][ct] = (f32x4){0.f, 0.f, 0.f, 0.f};

    const bf16x8 zfrag = {};
#pragma unroll
    for (int ks = 0; ks < 4; ++ks) {
        bf16x8 a[2];
#pragma unroll
        for (int rt = 0; rt < 2; ++rt) {
            int r = rowBase + rt * 16 + c;
            a[rt] = (r < N) ? a_frag_load(A + (size_t)r * HID + ks * 32 + q * 8)
                            : zfrag;
        }
#pragma unroll
        for (int ct = 0; ct < 8; ++ct) {
            bf16x8 b = *(const bf16x8*)&B[((((ks * 8 + ct) * 4 + q) * 16 + c) << 3)];
            acc[0][ct] = __builtin_amdgcn_mfma_f32_16x16x32_bf16(a[0], b, acc[0][ct], 0, 0, 0);
            acc[1][ct] = __builtin_amdgcn_mfma_f32_16x16x32_bf16(a[1], b, acc[1][ct], 0, 0, 0);
        }
    }
#pragma unroll
    for (int rt = 0; rt < 2; ++rt)
#pragma unroll
        for (int reg = 0; reg < 4; ++reg) {
            int r = rowBase + rt * 16 + q * 4 + reg;
            if (r < N) {
#pragma unroll
                for (int ct = 0; ct < 8; ++ct)
                    C[(size_t)r * HID + ct * 16 + c] = f2bf(acc[rt][ct][reg]);
            }
        }
}

// ---------------- mean-pool body (one wave per graph, 8-deep unroll) ---------
__device__ __forceinline__ void pool_body(const unsigned short* __restrict__ h,
                                          const int* __restrict__ gstart,
                                          float* __restrict__ pbuf,
                                          int layer, int g, int lane) {
    int s = gstart[g], e = gstart[g + 1];
    float sx[4] = {0.f, 0.f, 0.f, 0.f};
    float sy[4] = {0.f, 0.f, 0.f, 0.f};
    int v = s;
    for (; v + 7 < e; v += 8) {
        unsigned int pk[8];
#pragma unroll
        for (int u = 0; u < 8; ++u)
            pk[u] = ((const unsigned int*)(h + (size_t)(v + u) * HID))[lane];
#pragma unroll
        for (int u = 0; u < 8; ++u) {
            sx[u & 3] += bf2f((unsigned short)(pk[u] & 0xffffu));
            sy[u & 3] += bf2f((unsigned short)(pk[u] >> 16));
        }
    }
    for (; v < e; ++v) {
        unsigned int pk = ((const unsigned int*)(h + (size_t)v * HID))[lane];
        sx[0] += bf2f((unsigned short)(pk & 0xffffu));
        sy[0] += bf2f((unsigned short)(pk >> 16));
    }
    float inv = 1.0f / fmaxf((float)(e - s), 1.0f);
    float ox = ((sx[0] + sx[1]) + (sx[2] + sx[3])) * inv;
    float oy = ((sy[0] + sy[1]) + (sy[2] + sy[3])) * inv;
    float* dst = pbuf + (size_t)g * 640 + layer * HID + lane * 2;
    dst[0] = ox;
    dst[1] = oy;
}

// fat kernel: layer-0 GEMM (LDS-copied W) + XCD-SLICED flat CSR scatter.
// adj entries stay 8B int2 (r9 evidence). NEW: scatter blocks are sliced by
// destination range, slice = (blockIdx-gemmGrid)&7. Total grid is kept <=
// co-resident capacity (5 blocks/CU @ 32KB LDS -> 1280), so the round-robin
// blockIdx%8 -> XCD mapping is frozen for the whole kernel. All cursor
// atomics + adj stores for a given line then come from ONE XCD's L2 ->
// full-line writebacks instead of ~16 cross-XCD 8B partial merges (the
// mechanism behind WRITE_SIZE 129.5MB vs 39MB ideal). Each chunk-group of 8
// blocks re-reads its col[] chunk 8x (cheap, parallel reads).
__global__ __launch_bounds__(256) void k_fused0(const float* __restrict__ x,
                                                const unsigned short* __restrict__ Wg,
                                                unsigned short* __restrict__ buf0,
                                                const int* __restrict__ row,
                                                const int* __restrict__ col,
                                                const float* __restrict__ dinv,
                                                int* __restrict__ cursor,
                                                int2* __restrict__ adj,
                                                int E, int N, int gemmGrid) {
    __shared__ unsigned short Wsw[16384];   // 32 KB (gemm blocks only)
    if (blockIdx.x < gemmGrid) {
        const uint4* src = (const uint4*)Wg;   // straight 16B copy, 0 conflicts
        uint4* dst = (uint4*)Wsw;
        for (int i = threadIdx.x; i < 2048; i += 256) dst[i] = src[i];
        __syncthreads();
        gemm_body<float>(x, Wsw, buf0, N, blockIdx.x);
        return;
    }
    // ---- XCD-sliced scatter ----
    int sb = blockIdx.x - gemmGrid;
    int ng = (int)(gridDim.x - gemmGrid) >> 3;   // chunk groups
    int sl = sb & 7;                             // slice == XCD (heuristic only)
    int cg = sb >> 3;
    int sliceN = (N + 7) >> 3;
    int lo = sl * sliceN;
    int hi = lo + sliceN; if (hi > N) hi = N;
    int total = E + N;
    int stride = ng << 8;                        // ng * 256
    for (int i = (cg << 8) + threadIdx.x; i < total; i += stride) {
        int d = (i < E) ? col[i] : (i - E);
        if (d >= lo && d < hi) {
            int s = (i < E) ? row[i] : (i - E);  // self loop for i >= E
            int p = atomicAdd(&cursor[d], 1);
            adj[p] = make_int2(s, __float_as_int(dinv[s] * dinv[d]));
        }
    }
}

// layers 2..5 GEMM + pool rider. Pool of h_{L-1} reads the SAME buffer the
// GEMM reads (A) -> no race; riding here (not on the aggregate, which would
// overwrite A) hides 4 of the 5 pools.
__global__ __launch_bounds__(256) void k_gemm_pool(const unsigned short* __restrict__ A,
                                                   const unsigned short* __restrict__ Wg,
                                                   unsigned short* __restrict__ C,
                                                   int N,
                                                   const int* __restrict__ gstart,
                                                   float* __restrict__ pbuf,
                                                   int poolLayer, int G, int gemmGrid) {
    if (blockIdx.x < gemmGrid) {
        gemm_body<unsigned short>(A, Wg, C, N, blockIdx.x);
        return;
    }
    int g = (blockIdx.x - gemmGrid) * 4 + (threadIdx.x >> 6);
    if (g >= G) return;
    pool_body(A, gstart, pbuf, poolLayer, g, threadIdx.x & 63);
}

// ---------------- CSR gather-aggregate + bias + ReLU (16 rows in flight) -----
// One node per wave. Half-wave edge split: lanes 0-31 take even edges, lanes
// 32-63 odd; each lane loads 8B (4 features) of its row -> an 8-deep unroll
// keeps 16 rows in flight per wave. Tail = ONE masked batch (idx clamped to
// e-1, weight zeroed; clamped re-reads of a hot line are ~free, r3).
__global__ __launch_bounds__(256) void k_aggregate(const unsigned short* __restrict__ t,
                                                   const int* __restrict__ indptr,
                                                   const int2* __restrict__ adj,
                                                   const float* __restrict__ bias,
                                                   unsigned short* __restrict__ h, int N) {
    int node = blockIdx.x * 4 + (threadIdx.x >> 6);
    if (node >= N) return;
    int lane = threadIdx.x & 63;
    int half = lane >> 5;          // 0: even-indexed edges, 1: odd
    int fl   = lane & 31;          // feature quad: features 4*fl .. 4*fl+3
    int s = indptr[node], e = indptr[node + 1];   // e > s (self-loop)
    const unsigned long long* tu8 = (const unsigned long long*)t;  // 8B units

    float a0 = 0.f, a1 = 0.f, a2 = 0.f, a3 = 0.f;

    int p = s;
    for (; p + 15 < e; p += 16) {      // full batches: 16 edges/iter/wave
        unsigned long long v[8];
        float w[8];
#pragma unroll
        for (int u = 0; u < 8; ++u) {
            int2 ae = adj[p + 2 * u + half];
            w[u] = __int_as_float(ae.y);
            v[u] = tu8[(size_t)ae.x * 32 + fl];
        }
#pragma unroll
        for (int u = 0; u < 8; ++u) {
            unsigned int lo = (unsigned int)(v[u] & 0xffffffffULL);
            unsigned int hi = (unsigned int)(v[u] >> 32);
            a0 = fmaf(w[u], bf2f((unsigned short)(lo & 0xffffu)), a0);
            a1 = fmaf(w[u], bf2f((unsigned short)(lo >> 16)), a1);
            a2 = fmaf(w[u], bf2f((unsigned short)(hi & 0xffffu)), a2);
            a3 = fmaf(w[u], bf2f((unsigned short)(hi >> 16)), a3);
        }
    }
    if (p < e) {                        // one masked batch covers the tail
        unsigned long long v[8];
        float w[8];
#pragma unroll
        for (int u = 0; u < 8; ++u) {
            int idx = p + 2 * u + half;
            int2 ae = adj[idx < e ? idx : e - 1];
            w[u] = (idx < e) ? __int_as_float(ae.y) : 0.f;
            v[u] = tu8[(size_t)ae.x * 32 + fl];
        }
#pragma unroll
        for (int u = 0; u < 8; ++u) {
            unsigned int lo = (unsigned int)(v[u] & 0xffffffffULL);
            unsigned int hi = (unsigned int)(v[u] >> 32);
            a0 = fmaf(w[u], bf2f((unsigned short)(lo & 0xffffu)), a0);
            a1 = fmaf(w[u], bf2f((unsigned short)(lo >> 16)), a1);
            a2 = fmaf(w[u], bf2f((unsigned short)(hi & 0xffffu)), a2);
            a3 = fmaf(w[u], bf2f((unsigned short)(hi >> 16)), a3);
        }
    }
    // combine even/odd halves (partner lane = lane ^ 32, same fl)
    a0 += __shfl_xor(a0, 32);
    a1 += __shfl_xor(a1, 32);
    a2 += __shfl_xor(a2, 32);
    a3 += __shfl_xor(a3, 32);
    if (half == 0) {
        int fb = fl * 4;
        uint2 pk;
        pk.x = (unsigned int)f2bf(fmaxf(a0 + bias[fb + 0], 0.f)) |
               ((unsigned int)f2bf(fmaxf(a1 + bias[fb + 1], 0.f)) << 16);
        pk.y = (unsigned int)f2bf(fmaxf(a2 + bias[fb + 2], 0.f)) |
               ((unsigned int)f2bf(fmaxf(a3 + bias[fb + 3], 0.f)) << 16);
        ((uint2*)(h + (size_t)node * HID))[fl] = pk;   // 32 lanes x 8B = 256B
    }
}

// ---------------- standalone pool (used for the final layer) -----------------
__global__ __launch_bounds__(256) void k_pool(const unsigned short* __restrict__ h,
                                              const int* __restrict__ gstart,
                                              float* __restrict__ pbuf,
                                              int layer, int G) {
    int g = blockIdx.x * 4 + (threadIdx.x >> 6);
    if (g >= G) return;
    pool_body(h, gstart, pbuf, layer, g, threadIdx.x & 63);
}

// ---------------- MLP head: Z[G,640] = relu(P[G,640] @ Wl1 + bl1) ------------
__global__ __launch_bounds__(256) void k_head1(const float* __restrict__ P,
                                               const float* __restrict__ Wl1,
                                               const float* __restrict__ bl1,
                                               float* __restrict__ Z, int G) {
    __shared__ float As[64][68];
    __shared__ float Ws[64][64];
    const int tid = threadIdx.x;
    const int tr = tid >> 4;
    const int tc = tid & 15;
    const int gBase = blockIdx.x * 64;
    const int cBase = blockIdx.y * 64;

    float acc[4][4];
#pragma unroll
    for (int i = 0; i < 4; ++i)
#pragma unroll
        for (int j = 0; j < 4; ++j) acc[i][j] = 0.f;

    for (int kb = 0; kb < 640; kb += 64) {
#pragma unroll
        for (int i = 0; i < 4; ++i) {
            int f4 = tid + i * 256;
            int r  = f4 >> 4;
            int kc = (f4 & 15) << 2;
            int gg = gBase + r;
            float4 v = {0.f, 0.f, 0.f, 0.f};
            if (gg < G) v = *(const float4*)(P + (size_t)gg * 640 + kb + kc);
            As[kc + 0][r] = v.x; As[kc + 1][r] = v.y;
            As[kc + 2][r] = v.z; As[kc + 3][r] = v.w;
        }
#pragma unroll
        for (int i = 0; i < 4; ++i) {
            int f4 = tid + i * 256;
            int k  = f4 >> 4;
            int c4 = (f4 & 15) << 2;
            *(float4*)&Ws[k][c4] =
                *(const float4*)(Wl1 + (size_t)(kb + k) * 640 + cBase + c4);
        }
        __syncthreads();
#pragma unroll
        for (int k = 0; k < 64; ++k) {
            float a[4], w[4];
            *(float4*)&a[0] = *(const float4*)&As[k][tr * 4];
            *(float4*)&w[0] = *(const float4*)&Ws[k][tc * 4];
#pragma unroll
            for (int i = 0; i < 4; ++i)
#pragma unroll
                for (int j = 0; j < 4; ++j)
                    acc[i][j] = fmaf(a[i], w[j], acc[i][j]);
        }
        __syncthreads();
    }
#pragma unroll
    for (int i = 0; i < 4; ++i) {
        int gg = gBase + tr * 4 + i;
        if (gg < G) {
            float4 o;
            o.x = fmaxf(acc[i][0] + bl1[cBase + tc * 4 + 0], 0.f);
            o.y = fmaxf(acc[i][1] + bl1[cBase + tc * 4 + 1], 0.f);
            o.z = fmaxf(acc[i][2] + bl1[cBase + tc * 4 + 2], 0.f);
            o.w = fmaxf(acc[i][3] + bl1[cBase + tc * 4 + 3], 0.f);
            *(float4*)(Z + (size_t)gg * 640 + cBase + tc * 4) = o;
        }
    }
}

__global__ void k_fc2(const float* __restrict__ zbuf, const float* __restrict__ Wl2,
                      const float* __restrict__ bl2, float* __restrict__ out) {
    int g = blockIdx.x;
    int t = threadIdx.x;  // 128 threads = 2 waves
    float s = 0.f;
    for (int k = t; k < 640; k += 128) s = fmaf(zbuf[(size_t)g * 640 + k], Wl2[k], s);
#pragma unroll
    for (int off = 32; off > 0; off >>= 1) s += __shfl_down(s, off);
    __shared__ float ws[2];
    if ((t & 63) == 0) ws[t >> 6] = s;
    __syncthreads();
    if (t == 0) out[g] = ws[0] + ws[1] + bl2[0];
}

// ---------------- driver ----------------
extern "C" void kernel_launch(void* const* d_in, const int* in_sizes, int n_in,
                              void* d_out, int out_size, void* d_ws, size_t ws_size,
                              hipStream_t stream) {
    const float* x    = (const float*)d_in[0];
    const int*   edge = (const int*)d_in[1];
    const int*   bat  = (const int*)d_in[2];
    const float* W1   = (const float*)d_in[3];
    const float* b1   = (const float*)d_in[4];
    const float* W2   = (const float*)d_in[5];
    const float* b2   = (const float*)d_in[6];
    const float* W3   = (const float*)d_in[7];
    const float* b3   = (const float*)d_in[8];
    const float* W4   = (const float*)d_in[9];
    const float* b4   = (const float*)d_in[10];
    const float* Wl1  = (const float*)d_in[11];
    const float* bl1  = (const float*)d_in[12];
    const float* Wl2  = (const float*)d_in[13];
    const float* bl2  = (const float*)d_in[14];
    float*       out  = (float*)d_out;

    const int N = in_sizes[2];       // 100000
    const int E = in_sizes[1] / 2;   // 1600000
    const int G = out_size;          // 512
    (void)n_in; (void)ws_size;

    (void)hipGetLastError();  // clear any stale error

    // ---- workspace carve ----
    size_t off = 0;
    auto alloc = [&](size_t bytes) -> void* {
        void* p = (void*)((char*)d_ws + off);
        off += (bytes + 255) & ~(size_t)255;
        return p;
    };
    unsigned short* buf0 = (unsigned short*)alloc((size_t)N * HID * 2);  // t, bf16
    unsigned short* buf1 = (unsigned short*)alloc((size_t)N * HID * 2);  // h, bf16
    unsigned short* Wg   = (unsigned short*)alloc((size_t)4 * 16384 * 2); // swizzled W1..4
    float* dinv   = (float*)alloc((size_t)N * 4);
    int*   degI   = (int*)alloc((size_t)N * 4);
    int*   cursor = (int*)alloc((size_t)N * 4);
    int*   indptr = (int*)alloc((size_t)(N + 1) * 4);
    int*   partial= (int*)alloc((size_t)N * 4);
    int*   bsums  = (int*)alloc((size_t)1024 * 4);
    int2*  adj    = (int2*)alloc((size_t)(E + N) * 8);
    int*   gstart = (int*)alloc((size_t)(G + 1) * 4);
    float* pbuf   = (float*)alloc((size_t)G * 640 * 4);
    float* zbuf   = (float*)alloc((size_t)G * 640 * 4);

    const int* rowv = edge;      // sources
    const int* colv = edge + E;  // destinations

    // ---- preprocessing (merged) ----
    hipMemsetAsync(degI, 0, (size_t)N * 4, stream);
    const int degGrid = (E + 255) / 256;
    const int gbGrid  = (G + 256) / 256;
    k_prep<<<degGrid + 256 + gbGrid, 256, 0, stream>>>(colv, degI, W1, W2, W3, W4,
                                                       Wg, bat, gstart,
                                                       E, N, G, degGrid);
    const int scanBlocks = (N + 1023) / 1024;
    k_scan_part<<<scanBlocks, 1024, 0, stream>>>(degI, partial, bsums, N);
    k_scan_tops<<<1, 1024, 0, stream>>>(bsums, indptr, scanBlocks, N);
    k_scan_fix<<<(N + 255) / 256, 256, 0, stream>>>(partial, bsums, degI,
                                                    indptr, cursor, dinv, N);

    // ---- fused: layer-0 GEMM (LDS W) + XCD-sliced CSR scatter ----
    // Keep total grid <= 1280 (5 blocks/CU co-residency) so bid%8->XCD holds.
    const int gemmGrid = (N + 127) / 128;
    int scatBlocks = ((1280 - gemmGrid) / 8) * 8;
    if (scatBlocks < 8) scatBlocks = 8;
    k_fused0<<<gemmGrid + scatBlocks, 256, 0, stream>>>(x, Wg, buf0, rowv, colv,
                                                        dinv, cursor, adj,
                                                        E, N, gemmGrid);

    // ---- 5 GCN layers (layer 5 reuses W4/b4, matching the reference) ----
    const int aggGrid  = (N + 3) / 4;
    const int poolGrid = (G + 3) / 4;

    // layer 1
    k_aggregate<<<aggGrid, 256, 0, stream>>>(buf0, indptr, adj, b1, buf1, N);
    // layers 2..5: gemm (+ pool rider of previous h) then aggregate
    const float* bs_[4] = {b2, b3, b4, b4};
    const int Wi_[4] = {1, 2, 3, 3};
    for (int i = 0; i < 4; ++i) {
        k_gemm_pool<<<gemmGrid + poolGrid, 256, 0, stream>>>(
            buf1, Wg + Wi_[i] * 16384, buf0, N, gstart, pbuf, i, G, gemmGrid);
        k_aggregate<<<aggGrid, 256, 0, stream>>>(buf0, indptr, adj, bs_[i], buf1, N);
    }
    k_pool<<<poolGrid, 256, 0, stream>>>(buf1, gstart, pbuf, 4, G);

    // ---- MLP head ----
    dim3 hgrid((G + 63) / 64, 10);   // 640 output cols / 64
    k_head1<<<hgrid, 256, 0, stream>>>(pbuf, Wl1, bl1, zbuf, G);
    k_fc2<<<G, 128, 0, stream>>>(zbuf, Wl2, bl2, out);

    // sentinel: some launch failed synchronously (absmax ~= 48)
    if (hipGetLastError() != hipSuccess)
        hipMemsetAsync(d_out, 0x42, (size_t)out_size * 4, stream);
}

// Round 7
// 759.458 us; speedup vs baseline: 1.1575x; 1.1575x over previous
//
#include <hip/hip_runtime.h>
#include <hip/hip_fp16.h>

#define HID 128   // feature width (D == H == 128)

// ---------------- bf16 helpers ----------------
__device__ __forceinline__ float bf2f(unsigned short u) {
    union { unsigned int i; float f; } v;
    v.i = ((unsigned int)u) << 16;
    return v.f;
}
__device__ __forceinline__ unsigned short f2bf(float f) {
    union { float f; unsigned int i; } v;
    v.f = f;
    unsigned int lsb = (v.i >> 16) & 1u;
    v.i += 0x7fffu + lsb;   // round-to-nearest-even
    return (unsigned short)(v.i >> 16);
}

// ---------------- fp8 e4m3fn helpers ----------------
// t = h@W is stored fp8 (128B/row = one cache line): halves the aggregate's
// random-gather traffic, which sits at the L3 line-service wall (~4.7 TB/s).
// decode: hw v_cvt_f32_fp8 when available; else e4m3->f16 bit trick (x256
// folded back at use: here we just multiply, cheap).
template <int S>
__device__ __forceinline__ float fp8_dec(unsigned int v) {
#if __has_builtin(__builtin_amdgcn_cvt_f32_fp8)
    return __builtin_amdgcn_cvt_f32_fp8(v, S);
#else
    unsigned int b = (v >> (S * 8)) & 0xffu;
    unsigned short u = (unsigned short)(((b & 0x80u) << 8) | ((b & 0x7fu) << 7));
    return __half2float(__ushort_as_half(u)) * 256.0f;
#endif
}
// encode: clamp to +-448, f32->f16 (hw RNE), then RNE 10->3 mantissa bits.
__device__ __forceinline__ unsigned char fp8_enc(float f) {
    f = fminf(fmaxf(f, -448.f), 448.f);
    unsigned short u = __half_as_ushort(__float2half(f * 0.00390625f)); // /256
    unsigned short r = (unsigned short)(u + (((u >> 7) & 1u) + 0x3fu));
    return (unsigned char)(((r >> 7) & 0x7fu) | ((u >> 8) & 0x80u));
}

typedef __attribute__((ext_vector_type(8))) short bf16x8;   // 8 bf16 (4 VGPRs)
typedef __attribute__((ext_vector_type(4))) float f32x4;    // MFMA acc

// ---------------- merged preprocessing: deg + wprep + gbounds ---------------
__global__ void k_prep(const int* __restrict__ col, int* __restrict__ degI,
                       const float* __restrict__ W1, const float* __restrict__ W2,
                       const float* __restrict__ W3, const float* __restrict__ W4,
                       unsigned short* __restrict__ Wg,
                       const int* __restrict__ batch, int* __restrict__ gstart,
                       int E, int N, int G, int degGrid) {
    int bid = blockIdx.x;
    if (bid < degGrid) {                       // ---- degree histogram ----
        int i = bid * 256 + threadIdx.x;
        if (i < E) atomicAdd(&degI[col[i]], 1);
        return;
    }
    bid -= degGrid;
    if (bid < 256) {                           // ---- W pre-swizzle ----
        int m = bid >> 6;                      // matrix index 0..3
        int i = (bid & 63) * 256 + threadIdx.x;
        const float* Wm = (m == 0) ? W1 : (m == 1) ? W2 : (m == 2) ? W3 : W4;
        int k = i >> 7, n = i & 127;
        int ks = k >> 5, q = (k >> 3) & 3, j = k & 7;
        int ct = n >> 4, c = n & 15;
        Wg[m * 16384 + ((((ks * 8 + ct) * 4 + q) * 16 + c) << 3) + j] = f2bf(Wm[i]);
        return;
    }
    bid -= 256;                                // ---- graph bounds ----
    int g = bid * 256 + threadIdx.x;
    if (g > G) return;
    int lo = 0, hi = N;
    while (lo < hi) {
        int mid = (lo + hi) >> 1;
        if (batch[mid] < g) lo = mid + 1; else hi = mid;
    }
    gstart[g] = lo;
}

// ---- 3-phase device-wide exclusive scan of (degI[i]+1) -> indptr, cursor ----
__global__ void k_scan_part(const int* __restrict__ degI, int* __restrict__ partial,
                            int* __restrict__ sums, int N) {
    __shared__ int sh[1024];
    int tid = threadIdx.x;
    int i = blockIdx.x * 1024 + tid;
    int v = (i < N) ? (degI[i] + 1) : 0;
    sh[tid] = v;
    __syncthreads();
    for (int off = 1; off < 1024; off <<= 1) {
        int t = (tid >= off) ? sh[tid - off] : 0;
        __syncthreads();
        sh[tid] += t;
        __syncthreads();
    }
    if (i < N) partial[i] = sh[tid] - v;
    if (tid == 1023) sums[blockIdx.x] = sh[1023];
}
__global__ void k_scan_tops(int* __restrict__ sums, int* __restrict__ indptr,
                            int nblocks, int N) {
    __shared__ int sh[1024];
    int tid = threadIdx.x;
    int v = (tid < nblocks) ? sums[tid] : 0;
    sh[tid] = v;
    __syncthreads();
    for (int off = 1; off < 1024; off <<= 1) {
        int t = (tid >= off) ? sh[tid - off] : 0;
        __syncthreads();
        sh[tid] += t;
        __syncthreads();
    }
    if (tid < nblocks) sums[tid] = sh[tid] - v;   // exclusive
    if (tid == 1023) indptr[N] = sh[1023];        // grand total = E + N
}
// phase 3: emit indptr + cursor + dinv = 1/sqrt(deg+1)
__global__ void k_scan_fix(const int* __restrict__ partial, const int* __restrict__ sums,
                           const int* __restrict__ degI, int* __restrict__ indptr,
                           int* __restrict__ cursor, float* __restrict__ dinv, int N) {
    int i = blockIdx.x * blockDim.x + threadIdx.x;
    if (i < N) {
        int ex = partial[i] + sums[i >> 10];
        indptr[i] = ex;
        cursor[i] = ex;
        dinv[i] = 1.0f / sqrtf((float)(degI[i] + 1));
    }
}

// ---------------- MFMA GEMM body (C = A @ W, fp8 out) ------------------------
__device__ __forceinline__ bf16x8 a_frag_load(const unsigned short* p) {
    return *(const bf16x8*)p;
}
__device__ __forceinline__ bf16x8 a_frag_load(const float* p) {
    bf16x8 r;
#pragma unroll
    for (int i = 0; i < 8; ++i) r[i] = (short)f2bf(p[i]);
    return r;
}

template <typename TA>
__device__ __forceinline__ void gemm_body(const TA* __restrict__ A,
                                          const unsigned short* __restrict__ B,
                                          unsigned char* __restrict__ C,
                                          int N, int blk) {
    const int tid = threadIdx.x;
    const int lane = tid & 63, wave = tid >> 6;
    const int q = lane >> 4, c = lane & 15;
    const int rowBase = blk * 128 + wave * 32;

    f32x4 acc[2][8];
#pragma unroll
    for (int rt = 0; rt < 2; ++rt)
#pragma unroll
        for (int ct = 0; ct < 8; ++ct)
            acc[rt][ct] = (f32x4){0.f, 0.f, 0.f, 0.f};

    const bf16x8 zfrag = {};
#pragma unroll
    for (int ks = 0; ks < 4; ++ks) {
        bf16x8 a[2];
#pragma unroll
        for (int rt = 0; rt < 2; ++rt) {
            int r = rowBase + rt * 16 + c;
            a[rt] = (r < N) ? a_frag_load(A + (size_t)r * HID + ks * 32 + q * 8)
                            : zfrag;
        }
#pragma unroll
        for (int ct = 0; ct < 8; ++ct) {
            bf16x8 b = *(const bf16x8*)&B[((((ks * 8 + ct) * 4 + q) * 16 + c) << 3)];
            acc[0][ct] = __builtin_amdgcn_mfma_f32_16x16x32_bf16(a[0], b, acc[0][ct], 0, 0, 0);
            acc[1][ct] = __builtin_amdgcn_mfma_f32_16x16x32_bf16(a[1], b, acc[1][ct], 0, 0, 0);
        }
    }
#pragma unroll
    for (int rt = 0; rt < 2; ++rt)
#pragma unroll
        for (int reg = 0; reg < 4; ++reg) {
            int r = rowBase + rt * 16 + q * 4 + reg;
            if (r < N) {
#pragma unroll
                for (int ct = 0; ct < 8; ++ct)
                    C[(size_t)r * HID + ct * 16 + c] = fp8_enc(acc[rt][ct][reg]);
            }
        }
}

// ---------------- mean-pool body (one wave per graph, 8-deep unroll) ---------
__device__ __forceinline__ void pool_body(const unsigned short* __restrict__ h,
                                          const int* __restrict__ gstart,
                                          float* __restrict__ pbuf,
                                          int layer, int g, int lane) {
    int s = gstart[g], e = gstart[g + 1];
    float sx[4] = {0.f, 0.f, 0.f, 0.f};
    float sy[4] = {0.f, 0.f, 0.f, 0.f};
    int v = s;
    for (; v + 7 < e; v += 8) {
        unsigned int pk[8];
#pragma unroll
        for (int u = 0; u < 8; ++u)
            pk[u] = ((const unsigned int*)(h + (size_t)(v + u) * HID))[lane];
#pragma unroll
        for (int u = 0; u < 8; ++u) {
            sx[u & 3] += bf2f((unsigned short)(pk[u] & 0xffffu));
            sy[u & 3] += bf2f((unsigned short)(pk[u] >> 16));
        }
    }
    for (; v < e; ++v) {
        unsigned int pk = ((const unsigned int*)(h + (size_t)v * HID))[lane];
        sx[0] += bf2f((unsigned short)(pk & 0xffffu));
        sy[0] += bf2f((unsigned short)(pk >> 16));
    }
    float inv = 1.0f / fmaxf((float)(e - s), 1.0f);
    float ox = ((sx[0] + sx[1]) + (sx[2] + sx[3])) * inv;
    float oy = ((sy[0] + sy[1]) + (sy[2] + sy[3])) * inv;
    float* dst = pbuf + (size_t)g * 640 + layer * HID + lane * 2;
    dst[0] = ox;
    dst[1] = oy;
}

// fat kernel: layer-0 GEMM (LDS-copied W, fp8 out) + flat CSR scatter.
// Scatter is the r5/entry-proven form: one element per thread, full grid.
// adj entries stay 8B int2 (r9 evidence); r6 proved destination-slicing does
// NOT reduce the write merge traffic -- reverted.
__global__ __launch_bounds__(256) void k_fused0(const float* __restrict__ x,
                                                const unsigned short* __restrict__ Wg,
                                                unsigned char* __restrict__ buf0,
                                                const int* __restrict__ row,
                                                const int* __restrict__ col,
                                                const float* __restrict__ dinv,
                                                int* __restrict__ cursor,
                                                int2* __restrict__ adj,
                                                int E, int N, int gemmGrid) {
    __shared__ unsigned short Wsw[16384];   // 32 KB (gemm blocks only)
    if (blockIdx.x < gemmGrid) {
        const uint4* src = (const uint4*)Wg;   // straight 16B copy, 0 conflicts
        uint4* dst = (uint4*)Wsw;
        for (int i = threadIdx.x; i < 2048; i += 256) dst[i] = src[i];
        __syncthreads();
        gemm_body<float>(x, Wsw, buf0, N, blockIdx.x);
        return;
    }
    int e = (blockIdx.x - gemmGrid) * blockDim.x + threadIdx.x;
    if (e >= E + N) return;
    int s, d;
    if (e < E) { s = row[e]; d = col[e]; }
    else       { s = d = e - E; }          // self loop
    int p = atomicAdd(&cursor[d], 1);
    adj[p] = make_int2(s, __float_as_int(dinv[s] * dinv[d]));
}

// layers 2..5 GEMM (bf16 h in, fp8 t out) + pool rider on h_{L-1} (same
// buffer the GEMM reads -> no race); hides 4 of the 5 pools.
__global__ __launch_bounds__(256) void k_gemm_pool(const unsigned short* __restrict__ A,
                                                   const unsigned short* __restrict__ Wg,
                                                   unsigned char* __restrict__ C,
                                                   int N,
                                                   const int* __restrict__ gstart,
                                                   float* __restrict__ pbuf,
                                                   int poolLayer, int G, int gemmGrid) {
    if (blockIdx.x < gemmGrid) {
        gemm_body<unsigned short>(A, Wg, C, N, blockIdx.x);
        return;
    }
    int g = (blockIdx.x - gemmGrid) * 4 + (threadIdx.x >> 6);
    if (g >= G) return;
    pool_body(A, gstart, pbuf, poolLayer, g, threadIdx.x & 63);
}

// ---------------- CSR gather-aggregate + bias + ReLU (fp8 t, 16 rows/wave) ---
// One node per wave. Half-wave edge split: lanes 0-31 even edges, 32-63 odd;
// each lane loads 4B = 4 fp8 features of its row -> 8-deep unroll keeps 16
// rows (= 16 cache lines, rows are exactly 128B) in flight per wave.
// Tail = ONE masked batch (idx clamped to e-1, weight zeroed; r3-proven).
__global__ __launch_bounds__(256) void k_aggregate(const unsigned char* __restrict__ t,
                                                   const int* __restrict__ indptr,
                                                   const int2* __restrict__ adj,
                                                   const float* __restrict__ bias,
                                                   unsigned short* __restrict__ h, int N) {
    int node = blockIdx.x * 4 + (threadIdx.x >> 6);
    if (node >= N) return;
    int lane = threadIdx.x & 63;
    int half = lane >> 5;          // 0: even-indexed edges, 1: odd
    int fl   = lane & 31;          // feature quad: features 4*fl .. 4*fl+3
    int s = indptr[node], e = indptr[node + 1];   // e > s (self-loop)
    const unsigned int* tu4 = (const unsigned int*)t;  // 4B = 4 fp8 features

    float a0 = 0.f, a1 = 0.f, a2 = 0.f, a3 = 0.f;

    int p = s;
    for (; p + 15 < e; p += 16) {      // full batches: 16 edges/iter/wave
        unsigned int v[8];
        float w[8];
#pragma unroll
        for (int u = 0; u < 8; ++u) {
            int2 ae = adj[p + 2 * u + half];
            w[u] = __int_as_float(ae.y);
            v[u] = tu4[(size_t)ae.x * 32 + fl];
        }
#pragma unroll
        for (int u = 0; u < 8; ++u) {
            a0 = fmaf(w[u], fp8_dec<0>(v[u]), a0);
            a1 = fmaf(w[u], fp8_dec<1>(v[u]), a1);
            a2 = fmaf(w[u], fp8_dec<2>(v[u]), a2);
            a3 = fmaf(w[u], fp8_dec<3>(v[u]), a3);
        }
    }
    if (p < e) {                        // one masked batch covers the tail
        unsigned int v[8];
        float w[8];
#pragma unroll
        for (int u = 0; u < 8; ++u) {
            int idx = p + 2 * u + half;
            int2 ae = adj[idx < e ? idx : e - 1];
            w[u] = (idx < e) ? __int_as_float(ae.y) : 0.f;
            v[u] = tu4[(size_t)ae.x * 32 + fl];
        }
#pragma unroll
        for (int u = 0; u < 8; ++u) {
            a0 = fmaf(w[u], fp8_dec<0>(v[u]), a0);
            a1 = fmaf(w[u], fp8_dec<1>(v[u]), a1);
            a2 = fmaf(w[u], fp8_dec<2>(v[u]), a2);
            a3 = fmaf(w[u], fp8_dec<3>(v[u]), a3);
        }
    }
    // combine even/odd halves (partner lane = lane ^ 32, same fl)
    a0 += __shfl_xor(a0, 32);
    a1 += __shfl_xor(a1, 32);
    a2 += __shfl_xor(a2, 32);
    a3 += __shfl_xor(a3, 32);
    if (half == 0) {
        int fb = fl * 4;
        uint2 pk;
        pk.x = (unsigned int)f2bf(fmaxf(a0 + bias[fb + 0], 0.f)) |
               ((unsigned int)f2bf(fmaxf(a1 + bias[fb + 1], 0.f)) << 16);
        pk.y = (unsigned int)f2bf(fmaxf(a2 + bias[fb + 2], 0.f)) |
               ((unsigned int)f2bf(fmaxf(a3 + bias[fb + 3], 0.f)) << 16);
        ((uint2*)(h + (size_t)node * HID))[fl] = pk;   // 32 lanes x 8B = 256B
    }
}

// ---------------- standalone pool (used for the final layer) -----------------
__global__ __launch_bounds__(256) void k_pool(const unsigned short* __restrict__ h,
                                              const int* __restrict__ gstart,
                                              float* __restrict__ pbuf,
                                              int layer, int G) {
    int g = blockIdx.x * 4 + (threadIdx.x >> 6);
    if (g >= G) return;
    pool_body(h, gstart, pbuf, layer, g, threadIdx.x & 63);
}

// ---------------- MLP head: Z[G,640] = relu(P[G,640] @ Wl1 + bl1) ------------
__global__ __launch_bounds__(256) void k_head1(const float* __restrict__ P,
                                               const float* __restrict__ Wl1,
                                               const float* __restrict__ bl1,
                                               float* __restrict__ Z, int G) {
    __shared__ float As[64][68];
    __shared__ float Ws[64][64];
    const int tid = threadIdx.x;
    const int tr = tid >> 4;
    const int tc = tid & 15;
    const int gBase = blockIdx.x * 64;
    const int cBase = blockIdx.y * 64;

    float acc[4][4];
#pragma unroll
    for (int i = 0; i < 4; ++i)
#pragma unroll
        for (int j = 0; j < 4; ++j) acc[i][j] = 0.f;

    for (int kb = 0; kb < 640; kb += 64) {
#pragma unroll
        for (int i = 0; i < 4; ++i) {
            int f4 = tid + i * 256;
            int r  = f4 >> 4;
            int kc = (f4 & 15) << 2;
            int gg = gBase + r;
            float4 v = {0.f, 0.f, 0.f, 0.f};
            if (gg < G) v = *(const float4*)(P + (size_t)gg * 640 + kb + kc);
            As[kc + 0][r] = v.x; As[kc + 1][r] = v.y;
            As[kc + 2][r] = v.z; As[kc + 3][r] = v.w;
        }
#pragma unroll
        for (int i = 0; i < 4; ++i) {
            int f4 = tid + i * 256;
            int k  = f4 >> 4;
            int c4 = (f4 & 15) << 2;
            *(float4*)&Ws[k][c4] =
                *(const float4*)(Wl1 + (size_t)(kb + k) * 640 + cBase + c4);
        }
        __syncthreads();
#pragma unroll
        for (int k = 0; k < 64; ++k) {
            float a[4], w[4];
            *(float4*)&a[0] = *(const float4*)&As[k][tr * 4];
            *(float4*)&w[0] = *(const float4*)&Ws[k][tc * 4];
#pragma unroll
            for (int i = 0; i < 4; ++i)
#pragma unroll
                for (int j = 0; j < 4; ++j)
                    acc[i][j] = fmaf(a[i], w[j], acc[i][j]);
        }
        __syncthreads();
    }
#pragma unroll
    for (int i = 0; i < 4; ++i) {
        int gg = gBase + tr * 4 + i;
        if (gg < G) {
            float4 o;
            o.x = fmaxf(acc[i][0] + bl1[cBase + tc * 4 + 0], 0.f);
            o.y = fmaxf(acc[i][1] + bl1[cBase + tc * 4 + 1], 0.f);
            o.z = fmaxf(acc[i][2] + bl1[cBase + tc * 4 + 2], 0.f);
            o.w = fmaxf(acc[i][3] + bl1[cBase + tc * 4 + 3], 0.f);
            *(float4*)(Z + (size_t)gg * 640 + cBase + tc * 4) = o;
        }
    }
}

__global__ void k_fc2(const float* __restrict__ zbuf, const float* __restrict__ Wl2,
                      const float* __restrict__ bl2, float* __restrict__ out) {
    int g = blockIdx.x;
    int t = threadIdx.x;  // 128 threads = 2 waves
    float s = 0.f;
    for (int k = t; k < 640; k += 128) s = fmaf(zbuf[(size_t)g * 640 + k], Wl2[k], s);
#pragma unroll
    for (int off = 32; off > 0; off >>= 1) s += __shfl_down(s, off);
    __shared__ float ws[2];
    if ((t & 63) == 0) ws[t >> 6] = s;
    __syncthreads();
    if (t == 0) out[g] = ws[0] + ws[1] + bl2[0];
}

// ---------------- driver ----------------
extern "C" void kernel_launch(void* const* d_in, const int* in_sizes, int n_in,
                              void* d_out, int out_size, void* d_ws, size_t ws_size,
                              hipStream_t stream) {
    const float* x    = (const float*)d_in[0];
    const int*   edge = (const int*)d_in[1];
    const int*   bat  = (const int*)d_in[2];
    const float* W1   = (const float*)d_in[3];
    const float* b1   = (const float*)d_in[4];
    const float* W2   = (const float*)d_in[5];
    const float* b2   = (const float*)d_in[6];
    const float* W3   = (const float*)d_in[7];
    const float* b3   = (const float*)d_in[8];
    const float* W4   = (const float*)d_in[9];
    const float* b4   = (const float*)d_in[10];
    const float* Wl1  = (const float*)d_in[11];
    const float* bl1  = (const float*)d_in[12];
    const float* Wl2  = (const float*)d_in[13];
    const float* bl2  = (const float*)d_in[14];
    float*       out  = (float*)d_out;

    const int N = in_sizes[2];       // 100000
    const int E = in_sizes[1] / 2;   // 1600000
    const int G = out_size;          // 512
    (void)n_in; (void)ws_size;

    (void)hipGetLastError();  // clear any stale error

    // ---- workspace carve ----
    size_t off = 0;
    auto alloc = [&](size_t bytes) -> void* {
        void* p = (void*)((char*)d_ws + off);
        off += (bytes + 255) & ~(size_t)255;
        return p;
    };
    unsigned char*  buf0 = (unsigned char*)alloc((size_t)N * HID);       // t, fp8
    unsigned short* buf1 = (unsigned short*)alloc((size_t)N * HID * 2);  // h, bf16
    unsigned short* Wg   = (unsigned short*)alloc((size_t)4 * 16384 * 2); // swizzled W1..4
    float* dinv   = (float*)alloc((size_t)N * 4);
    int*   degI   = (int*)alloc((size_t)N * 4);
    int*   cursor = (int*)alloc((size_t)N * 4);
    int*   indptr = (int*)alloc((size_t)(N + 1) * 4);
    int*   partial= (int*)alloc((size_t)N * 4);
    int*   bsums  = (int*)alloc((size_t)1024 * 4);
    int2*  adj    = (int2*)alloc((size_t)(E + N) * 8);
    int*   gstart = (int*)alloc((size_t)(G + 1) * 4);
    float* pbuf   = (float*)alloc((size_t)G * 640 * 4);
    float* zbuf   = (float*)alloc((size_t)G * 640 * 4);

    const int* rowv = edge;      // sources
    const int* colv = edge + E;  // destinations

    // ---- preprocessing (merged) ----
    hipMemsetAsync(degI, 0, (size_t)N * 4, stream);
    const int degGrid = (E + 255) / 256;
    const int gbGrid  = (G + 256) / 256;
    k_prep<<<degGrid + 256 + gbGrid, 256, 0, stream>>>(colv, degI, W1, W2, W3, W4,
                                                       Wg, bat, gstart,
                                                       E, N, G, degGrid);
    const int scanBlocks = (N + 1023) / 1024;
    k_scan_part<<<scanBlocks, 1024, 0, stream>>>(degI, partial, bsums, N);
    k_scan_tops<<<1, 1024, 0, stream>>>(bsums, indptr, scanBlocks, N);
    k_scan_fix<<<(N + 255) / 256, 256, 0, stream>>>(partial, bsums, degI,
                                                    indptr, cursor, dinv, N);

    // ---- fused: layer-0 GEMM (LDS W, fp8 out) + CSR scatter (r5 form) ----
    const int gemmGrid = (N + 127) / 128;
    const int scatGrid = (E + N + 255) / 256;
    k_fused0<<<gemmGrid + scatGrid, 256, 0, stream>>>(x, Wg, buf0, rowv, colv,
                                                      dinv, cursor, adj,
                                                      E, N, gemmGrid);

    // ---- 5 GCN layers (layer 5 reuses W4/b4, matching the reference) ----
    const int aggGrid  = (N + 3) / 4;
    const int poolGrid = (G + 3) / 4;

    // layer 1
    k_aggregate<<<aggGrid, 256, 0, stream>>>(buf0, indptr, adj, b1, buf1, N);
    // layers 2..5: gemm (+ pool rider of previous h) then aggregate
    const float* bs_[4] = {b2, b3, b4, b4};
    const int Wi_[4] = {1, 2, 3, 3};
    for (int i = 0; i < 4; ++i) {
        k_gemm_pool<<<gemmGrid + poolGrid, 256, 0, stream>>>(
            buf1, Wg + Wi_[i] * 16384, buf0, N, gstart, pbuf, i, G, gemmGrid);
        k_aggregate<<<aggGrid, 256, 0, stream>>>(buf0, indptr, adj, bs_[i], buf1, N);
    }
    k_pool<<<poolGrid, 256, 0, stream>>>(buf1, gstart, pbuf, 4, G);

    // ---- MLP head ----
    dim3 hgrid((G + 63) / 64, 10);   // 640 output cols / 64
    k_head1<<<hgrid, 256, 0, stream>>>(pbuf, Wl1, bl1, zbuf, G);
    k_fc2<<<G, 128, 0, stream>>>(zbuf, Wl2, bl2, out);

    // sentinel: some launch failed synchronously (absmax ~= 48)
    if (hipGetLastError() != hipSuccess)
        hipMemsetAsync(d_out, 0x42, (size_t)out_size * 4, stream);
}

// Round 8
// 654.115 us; speedup vs baseline: 1.3439x; 1.1610x over previous
//
#include <hip/hip_runtime.h>
#include <hip/hip_fp16.h>

#define HID 128   // feature width (D == H == 128)

// ---------------- bf16 helpers ----------------
__device__ __forceinline__ float bf2f(unsigned short u) {
    union { unsigned int i; float f; } v;
    v.i = ((unsigned int)u) << 16;
    return v.f;
}
__device__ __forceinline__ unsigned short f2bf(float f) {
    union { float f; unsigned int i; } v;
    v.f = f;
    unsigned int lsb = (v.i >> 16) & 1u;
    v.i += 0x7fffu + lsb;   // round-to-nearest-even
    return (unsigned short)(v.i >> 16);
}

// ---------------- fp8 e4m3fn helpers ----------------
// t = h@W is stored fp8 (128B/row = one cache line = exactly 32 lanes x 4B).
template <int S>
__device__ __forceinline__ float fp8_dec(unsigned int v) {
#if __has_builtin(__builtin_amdgcn_cvt_f32_fp8)
    return __builtin_amdgcn_cvt_f32_fp8(v, S);
#else
    unsigned int b = (v >> (S * 8)) & 0xffu;
    unsigned short u = (unsigned short)(((b & 0x80u) << 8) | ((b & 0x7fu) << 7));
    return __half2float(__ushort_as_half(u)) * 256.0f;
#endif
}
// encode: clamp to +-448, f32->f16 (hw RNE), then RNE 10->3 mantissa bits.
__device__ __forceinline__ unsigned char fp8_enc(float f) {
    f = fminf(fmaxf(f, -448.f), 448.f);
    unsigned short u = __half_as_ushort(__float2half(f * 0.00390625f)); // /256
    unsigned short r = (unsigned short)(u + (((u >> 7) & 1u) + 0x3fu));
    return (unsigned char)(((r >> 7) & 0x7fu) | ((u >> 8) & 0x80u));
}

typedef __attribute__((ext_vector_type(8))) short bf16x8;   // 8 bf16 (4 VGPRs)
typedef __attribute__((ext_vector_type(4))) float f32x4;    // MFMA acc

// ---------------- merged preprocessing: deg + wprep + gbounds ---------------
__global__ void k_prep(const int* __restrict__ col, int* __restrict__ degI,
                       const float* __restrict__ W1, const float* __restrict__ W2,
                       const float* __restrict__ W3, const float* __restrict__ W4,
                       unsigned short* __restrict__ Wg,
                       const int* __restrict__ batch, int* __restrict__ gstart,
                       int E, int N, int G, int degGrid) {
    int bid = blockIdx.x;
    if (bid < degGrid) {                       // ---- degree histogram ----
        int i = bid * 256 + threadIdx.x;
        if (i < E) atomicAdd(&degI[col[i]], 1);
        return;
    }
    bid -= degGrid;
    if (bid < 256) {                           // ---- W pre-swizzle ----
        int m = bid >> 6;                      // matrix index 0..3
        int i = (bid & 63) * 256 + threadIdx.x;
        const float* Wm = (m == 0) ? W1 : (m == 1) ? W2 : (m == 2) ? W3 : W4;
        int k = i >> 7, n = i & 127;
        int ks = k >> 5, q = (k >> 3) & 3, j = k & 7;
        int ct = n >> 4, c = n & 15;
        Wg[m * 16384 + ((((ks * 8 + ct) * 4 + q) * 16 + c) << 3) + j] = f2bf(Wm[i]);
        return;
    }
    bid -= 256;                                // ---- graph bounds ----
    int g = bid * 256 + threadIdx.x;
    if (g > G) return;
    int lo = 0, hi = N;
    while (lo < hi) {
        int mid = (lo + hi) >> 1;
        if (batch[mid] < g) lo = mid + 1; else hi = mid;
    }
    gstart[g] = lo;
}

// ---- 3-phase device-wide exclusive scan of (degI[i]+1) -> indptr, cursor ----
__global__ void k_scan_part(const int* __restrict__ degI, int* __restrict__ partial,
                            int* __restrict__ sums, int N) {
    __shared__ int sh[1024];
    int tid = threadIdx.x;
    int i = blockIdx.x * 1024 + tid;
    int v = (i < N) ? (degI[i] + 1) : 0;
    sh[tid] = v;
    __syncthreads();
    for (int off = 1; off < 1024; off <<= 1) {
        int t = (tid >= off) ? sh[tid - off] : 0;
        __syncthreads();
        sh[tid] += t;
        __syncthreads();
    }
    if (i < N) partial[i] = sh[tid] - v;
    if (tid == 1023) sums[blockIdx.x] = sh[1023];
}
__global__ void k_scan_tops(int* __restrict__ sums, int* __restrict__ indptr,
                            int nblocks, int N) {
    __shared__ int sh[1024];
    int tid = threadIdx.x;
    int v = (tid < nblocks) ? sums[tid] : 0;
    sh[tid] = v;
    __syncthreads();
    for (int off = 1; off < 1024; off <<= 1) {
        int t = (tid >= off) ? sh[tid - off] : 0;
        __syncthreads();
        sh[tid] += t;
        __syncthreads();
    }
    if (tid < nblocks) sums[tid] = sh[tid] - v;   // exclusive
    if (tid == 1023) indptr[N] = sh[1023];        // grand total = E + N
}
// phase 3: emit indptr + cursor + dinv = 1/sqrt(deg+1)
__global__ void k_scan_fix(const int* __restrict__ partial, const int* __restrict__ sums,
                           const int* __restrict__ degI, int* __restrict__ indptr,
                           int* __restrict__ cursor, float* __restrict__ dinv, int N) {
    int i = blockIdx.x * blockDim.x + threadIdx.x;
    if (i < N) {
        int ex = partial[i] + sums[i >> 10];
        indptr[i] = ex;
        cursor[i] = ex;
        dinv[i] = 1.0f / sqrtf((float)(degI[i] + 1));
    }
}

// ---------------- MFMA GEMM body (C = A @ W, fp8 out) ------------------------
__device__ __forceinline__ bf16x8 a_frag_load(const unsigned short* p) {
    return *(const bf16x8*)p;
}
__device__ __forceinline__ bf16x8 a_frag_load(const float* p) {
    bf16x8 r;
#pragma unroll
    for (int i = 0; i < 8; ++i) r[i] = (short)f2bf(p[i]);
    return r;
}

template <typename TA>
__device__ __forceinline__ void gemm_body(const TA* __restrict__ A,
                                          const unsigned short* __restrict__ B,
                                          unsigned char* __restrict__ C,
                                          int N, int blk) {
    const int tid = threadIdx.x;
    const int lane = tid & 63, wave = tid >> 6;
    const int q = lane >> 4, c = lane & 15;
    const int rowBase = blk * 128 + wave * 32;

    f32x4 acc[2][8];
#pragma unroll
    for (int rt = 0; rt < 2; ++rt)
#pragma unroll
        for (int ct = 0; ct < 8; ++ct)
            acc[rt][ct] = (f32x4){0.f, 0.f, 0.f, 0.f};

    const bf16x8 zfrag = {};
#pragma unroll
    for (int ks = 0; ks < 4; ++ks) {
        bf16x8 a[2];
#pragma unroll
        for (int rt = 0; rt < 2; ++rt) {
            int r = rowBase + rt * 16 + c;
            a[rt] = (r < N) ? a_frag_load(A + (size_t)r * HID + ks * 32 + q * 8)
                            : zfrag;
        }
#pragma unroll
        for (int ct = 0; ct < 8; ++ct) {
            bf16x8 b = *(const bf16x8*)&B[((((ks * 8 + ct) * 4 + q) * 16 + c) << 3)];
            acc[0][ct] = __builtin_amdgcn_mfma_f32_16x16x32_bf16(a[0], b, acc[0][ct], 0, 0, 0);
            acc[1][ct] = __builtin_amdgcn_mfma_f32_16x16x32_bf16(a[1], b, acc[1][ct], 0, 0, 0);
        }
    }
#pragma unroll
    for (int rt = 0; rt < 2; ++rt)
#pragma unroll
        for (int reg = 0; reg < 4; ++reg) {
            int r = rowBase + rt * 16 + q * 4 + reg;
            if (r < N) {
#pragma unroll
                for (int ct = 0; ct < 8; ++ct)
                    C[(size_t)r * HID + ct * 16 + c] = fp8_enc(acc[rt][ct][reg]);
            }
        }
}

// ---------------- mean-pool body (one wave per graph, 8-deep unroll) ---------
__device__ __forceinline__ void pool_body(const unsigned short* __restrict__ h,
                                          const int* __restrict__ gstart,
                                          float* __restrict__ pbuf,
                                          int layer, int g, int lane) {
    int s = gstart[g], e = gstart[g + 1];
    float sx[4] = {0.f, 0.f, 0.f, 0.f};
    float sy[4] = {0.f, 0.f, 0.f, 0.f};
    int v = s;
    for (; v + 7 < e; v += 8) {
        unsigned int pk[8];
#pragma unroll
        for (int u = 0; u < 8; ++u)
            pk[u] = ((const unsigned int*)(h + (size_t)(v + u) * HID))[lane];
#pragma unroll
        for (int u = 0; u < 8; ++u) {
            sx[u & 3] += bf2f((unsigned short)(pk[u] & 0xffffu));
            sy[u & 3] += bf2f((unsigned short)(pk[u] >> 16));
        }
    }
    for (; v < e; ++v) {
        unsigned int pk = ((const unsigned int*)(h + (size_t)v * HID))[lane];
        sx[0] += bf2f((unsigned short)(pk & 0xffffu));
        sy[0] += bf2f((unsigned short)(pk >> 16));
    }
    float inv = 1.0f / fmaxf((float)(e - s), 1.0f);
    float ox = ((sx[0] + sx[1]) + (sx[2] + sx[3])) * inv;
    float oy = ((sy[0] + sy[1]) + (sy[2] + sy[3])) * inv;
    float* dst = pbuf + (size_t)g * 640 + layer * HID + lane * 2;
    dst[0] = ox;
    dst[1] = oy;
}

// fat kernel: layer-0 GEMM (LDS-copied W, fp8 out) + flat CSR scatter.
// Scatter is the r5/entry-proven form: one element per thread, full grid.
// adj entries stay 8B int2 (r9 evidence); r6 proved destination-slicing does
// NOT reduce the write merge traffic -- reverted.
__global__ __launch_bounds__(256) void k_fused0(const float* __restrict__ x,
                                                const unsigned short* __restrict__ Wg,
                                                unsigned char* __restrict__ buf0,
                                                const int* __restrict__ row,
                                                const int* __restrict__ col,
                                                const float* __restrict__ dinv,
                                                int* __restrict__ cursor,
                                                int2* __restrict__ adj,
                                                int E, int N, int gemmGrid) {
    __shared__ unsigned short Wsw[16384];   // 32 KB (gemm blocks only)
    if (blockIdx.x < gemmGrid) {
        const uint4* src = (const uint4*)Wg;   // straight 16B copy, 0 conflicts
        uint4* dst = (uint4*)Wsw;
        for (int i = threadIdx.x; i < 2048; i += 256) dst[i] = src[i];
        __syncthreads();
        gemm_body<float>(x, Wsw, buf0, N, blockIdx.x);
        return;
    }
    int e = (blockIdx.x - gemmGrid) * blockDim.x + threadIdx.x;
    if (e >= E + N) return;
    int s, d;
    if (e < E) { s = row[e]; d = col[e]; }
    else       { s = d = e - E; }          // self loop
    int p = atomicAdd(&cursor[d], 1);
    adj[p] = make_int2(s, __float_as_int(dinv[s] * dinv[d]));
}

// layers 2..5 GEMM (bf16 h in, fp8 t out) + pool rider on h_{L-1} (same
// buffer the GEMM reads -> no race); hides 4 of the 5 pools.
__global__ __launch_bounds__(256) void k_gemm_pool(const unsigned short* __restrict__ A,
                                                   const unsigned short* __restrict__ Wg,
                                                   unsigned char* __restrict__ C,
                                                   int N,
                                                   const int* __restrict__ gstart,
                                                   float* __restrict__ pbuf,
                                                   int poolLayer, int G, int gemmGrid) {
    if (blockIdx.x < gemmGrid) {
        gemm_body<unsigned short>(A, Wg, C, N, blockIdx.x);
        return;
    }
    int g = (blockIdx.x - gemmGrid) * 4 + (threadIdx.x >> 6);
    if (g >= G) return;
    pool_body(A, gstart, pbuf, poolLayer, g, threadIdx.x & 63);
}

// ---------------- CSR gather-aggregate + bias + ReLU (fp8, half-wave/node) ---
// fp8 row = 128B = exactly 32 lanes x 4B -> ONE NODE PER HALF-WAVE: lanes 0-31
// own node A, 32-63 own node B. Each half-wave runs its own 8-deep unroll
// (8 outstanding row-loads), so each wave carries TWO independent
// indptr->adj->gather chains (16 outstanding loads across 2 chains) -- the
// r5/r7 evidence says bytes/lines/in-flight-depth are NOT the limit; the
// serial per-node chain is the remaining suspect. 8 nodes/block halves the
// grid (12500): half the sequential block-rounds per CU. No cross-half
// shuffle combine; every lane stores (full 256B bf16 row per half-wave).
// Tail = ONE masked batch (idx clamped to e-1 -> real row, finite fp8;
// weight zeroed; r3-proven ~free).
__global__ __launch_bounds__(256) void k_aggregate(const unsigned char* __restrict__ t,
                                                   const int* __restrict__ indptr,
                                                   const int2* __restrict__ adj,
                                                   const float* __restrict__ bias,
                                                   unsigned short* __restrict__ h, int N) {
    int node = blockIdx.x * 8 + (threadIdx.x >> 5);   // half-wave index 0..7
    if (node >= N) return;
    int fl = threadIdx.x & 31;         // feature quad: features 4*fl .. 4*fl+3
    int s = indptr[node], e = indptr[node + 1];   // e > s (self-loop)
    const unsigned int* tu4 = (const unsigned int*)t;  // 4B = 4 fp8 features

    float a0 = 0.f, a1 = 0.f, a2 = 0.f, a3 = 0.f;

    int p = s;
    for (; p + 7 < e; p += 8) {        // full batches: 8 edges per half-wave
        unsigned int v[8];
        float w[8];
#pragma unroll
        for (int u = 0; u < 8; ++u) {
            int2 ae = adj[p + u];      // uniform per half-wave -> broadcast
            w[u] = __int_as_float(ae.y);
            v[u] = tu4[(size_t)ae.x * 32 + fl];
        }
#pragma unroll
        for (int u = 0; u < 8; ++u) {
            a0 = fmaf(w[u], fp8_dec<0>(v[u]), a0);
            a1 = fmaf(w[u], fp8_dec<1>(v[u]), a1);
            a2 = fmaf(w[u], fp8_dec<2>(v[u]), a2);
            a3 = fmaf(w[u], fp8_dec<3>(v[u]), a3);
        }
    }
    if (p < e) {                        // one masked batch covers the tail
        unsigned int v[8];
        float w[8];
#pragma unroll
        for (int u = 0; u < 8; ++u) {
            int idx = p + u;
            int2 ae = adj[idx < e ? idx : e - 1];
            w[u] = (idx < e) ? __int_as_float(ae.y) : 0.f;
            v[u] = tu4[(size_t)ae.x * 32 + fl];
        }
#pragma unroll
        for (int u = 0; u < 8; ++u) {
            a0 = fmaf(w[u], fp8_dec<0>(v[u]), a0);
            a1 = fmaf(w[u], fp8_dec<1>(v[u]), a1);
            a2 = fmaf(w[u], fp8_dec<2>(v[u]), a2);
            a3 = fmaf(w[u], fp8_dec<3>(v[u]), a3);
        }
    }
    int fb = fl * 4;
    uint2 pk;
    pk.x = (unsigned int)f2bf(fmaxf(a0 + bias[fb + 0], 0.f)) |
           ((unsigned int)f2bf(fmaxf(a1 + bias[fb + 1], 0.f)) << 16);
    pk.y = (unsigned int)f2bf(fmaxf(a2 + bias[fb + 2], 0.f)) |
           ((unsigned int)f2bf(fmaxf(a3 + bias[fb + 3], 0.f)) << 16);
    ((uint2*)(h + (size_t)node * HID))[fl] = pk;   // 32 lanes x 8B = 256B
}

// ---------------- standalone pool (used for the final layer) -----------------
__global__ __launch_bounds__(256) void k_pool(const unsigned short* __restrict__ h,
                                              const int* __restrict__ gstart,
                                              float* __restrict__ pbuf,
                                              int layer, int G) {
    int g = blockIdx.x * 4 + (threadIdx.x >> 6);
    if (g >= G) return;
    pool_body(h, gstart, pbuf, layer, g, threadIdx.x & 63);
}

// ---------------- MLP head: Z[G,640] = relu(P[G,640] @ Wl1 + bl1) ------------
__global__ __launch_bounds__(256) void k_head1(const float* __restrict__ P,
                                               const float* __restrict__ Wl1,
                                               const float* __restrict__ bl1,
                                               float* __restrict__ Z, int G) {
    __shared__ float As[64][68];
    __shared__ float Ws[64][64];
    const int tid = threadIdx.x;
    const int tr = tid >> 4;
    const int tc = tid & 15;
    const int gBase = blockIdx.x * 64;
    const int cBase = blockIdx.y * 64;

    float acc[4][4];
#pragma unroll
    for (int i = 0; i < 4; ++i)
#pragma unroll
        for (int j = 0; j < 4; ++j) acc[i][j] = 0.f;

    for (int kb = 0; kb < 640; kb += 64) {
#pragma unroll
        for (int i = 0; i < 4; ++i) {
            int f4 = tid + i * 256;
            int r  = f4 >> 4;
            int kc = (f4 & 15) << 2;
            int gg = gBase + r;
            float4 v = {0.f, 0.f, 0.f, 0.f};
            if (gg < G) v = *(const float4*)(P + (size_t)gg * 640 + kb + kc);
            As[kc + 0][r] = v.x; As[kc + 1][r] = v.y;
            As[kc + 2][r] = v.z; As[kc + 3][r] = v.w;
        }
#pragma unroll
        for (int i = 0; i < 4; ++i) {
            int f4 = tid + i * 256;
            int k  = f4 >> 4;
            int c4 = (f4 & 15) << 2;
            *(float4*)&Ws[k][c4] =
                *(const float4*)(Wl1 + (size_t)(kb + k) * 640 + cBase + c4);
        }
        __syncthreads();
#pragma unroll
        for (int k = 0; k < 64; ++k) {
            float a[4], w[4];
            *(float4*)&a[0] = *(const float4*)&As[k][tr * 4];
            *(float4*)&w[0] = *(const float4*)&Ws[k][tc * 4];
#pragma unroll
            for (int i = 0; i < 4; ++i)
#pragma unroll
                for (int j = 0; j < 4; ++j)
                    acc[i][j] = fmaf(a[i], w[j], acc[i][j]);
        }
        __syncthreads();
    }
#pragma unroll
    for (int i = 0; i < 4; ++i) {
        int gg = gBase + tr * 4 + i;
        if (gg < G) {
            float4 o;
            o.x = fmaxf(acc[i][0] + bl1[cBase + tc * 4 + 0], 0.f);
            o.y = fmaxf(acc[i][1] + bl1[cBase + tc * 4 + 1], 0.f);
            o.z = fmaxf(acc[i][2] + bl1[cBase + tc * 4 + 2], 0.f);
            o.w = fmaxf(acc[i][3] + bl1[cBase + tc * 4 + 3], 0.f);
            *(float4*)(Z + (size_t)gg * 640 + cBase + tc * 4) = o;
        }
    }
}

__global__ void k_fc2(const float* __restrict__ zbuf, const float* __restrict__ Wl2,
                      const float* __restrict__ bl2, float* __restrict__ out) {
    int g = blockIdx.x;
    int t = threadIdx.x;  // 128 threads = 2 waves
    float s = 0.f;
    for (int k = t; k < 640; k += 128) s = fmaf(zbuf[(size_t)g * 640 + k], Wl2[k], s);
#pragma unroll
    for (int off = 32; off > 0; off >>= 1) s += __shfl_down(s, off);
    __shared__ float ws[2];
    if ((t & 63) == 0) ws[t >> 6] = s;
    __syncthreads();
    if (t == 0) out[g] = ws[0] + ws[1] + bl2[0];
}

// ---------------- driver ----------------
extern "C" void kernel_launch(void* const* d_in, const int* in_sizes, int n_in,
                              void* d_out, int out_size, void* d_ws, size_t ws_size,
                              hipStream_t stream) {
    const float* x    = (const float*)d_in[0];
    const int*   edge = (const int*)d_in[1];
    const int*   bat  = (const int*)d_in[2];
    const float* W1   = (const float*)d_in[3];
    const float* b1   = (const float*)d_in[4];
    const float* W2   = (const float*)d_in[5];
    const float* b2   = (const float*)d_in[6];
    const float* W3   = (const float*)d_in[7];
    const float* b3   = (const float*)d_in[8];
    const float* W4   = (const float*)d_in[9];
    const float* b4   = (const float*)d_in[10];
    const float* Wl1  = (const float*)d_in[11];
    const float* bl1  = (const float*)d_in[12];
    const float* Wl2  = (const float*)d_in[13];
    const float* bl2  = (const float*)d_in[14];
    float*       out  = (float*)d_out;

    const int N = in_sizes[2];       // 100000
    const int E = in_sizes[1] / 2;   // 1600000
    const int G = out_size;          // 512
    (void)n_in; (void)ws_size;

    (void)hipGetLastError();  // clear any stale error

    // ---- workspace carve ----
    size_t off = 0;
    auto alloc = [&](size_t bytes) -> void* {
        void* p = (void*)((char*)d_ws + off);
        off += (bytes + 255) & ~(size_t)255;
        return p;
    };
    unsigned char*  buf0 = (unsigned char*)alloc((size_t)N * HID);       // t, fp8
    unsigned short* buf1 = (unsigned short*)alloc((size_t)N * HID * 2);  // h, bf16
    unsigned short* Wg   = (unsigned short*)alloc((size_t)4 * 16384 * 2); // swizzled W1..4
    float* dinv   = (float*)alloc((size_t)N * 4);
    int*   degI   = (int*)alloc((size_t)N * 4);
    int*   cursor = (int*)alloc((size_t)N * 4);
    int*   indptr = (int*)alloc((size_t)(N + 1) * 4);
    int*   partial= (int*)alloc((size_t)N * 4);
    int*   bsums  = (int*)alloc((size_t)1024 * 4);
    int2*  adj    = (int2*)alloc((size_t)(E + N) * 8);
    int*   gstart = (int*)alloc((size_t)(G + 1) * 4);
    float* pbuf   = (float*)alloc((size_t)G * 640 * 4);
    float* zbuf   = (float*)alloc((size_t)G * 640 * 4);

    const int* rowv = edge;      // sources
    const int* colv = edge + E;  // destinations

    // ---- preprocessing (merged) ----
    hipMemsetAsync(degI, 0, (size_t)N * 4, stream);
    const int degGrid = (E + 255) / 256;
    const int gbGrid  = (G + 256) / 256;
    k_prep<<<degGrid + 256 + gbGrid, 256, 0, stream>>>(colv, degI, W1, W2, W3, W4,
                                                       Wg, bat, gstart,
                                                       E, N, G, degGrid);
    const int scanBlocks = (N + 1023) / 1024;
    k_scan_part<<<scanBlocks, 1024, 0, stream>>>(degI, partial, bsums, N);
    k_scan_tops<<<1, 1024, 0, stream>>>(bsums, indptr, scanBlocks, N);
    k_scan_fix<<<(N + 255) / 256, 256, 0, stream>>>(partial, bsums, degI,
                                                    indptr, cursor, dinv, N);

    // ---- fused: layer-0 GEMM (LDS W, fp8 out) + CSR scatter (r5 form) ----
    const int gemmGrid = (N + 127) / 128;
    const int scatGrid = (E + N + 255) / 256;
    k_fused0<<<gemmGrid + scatGrid, 256, 0, stream>>>(x, Wg, buf0, rowv, colv,
                                                      dinv, cursor, adj,
                                                      E, N, gemmGrid);

    // ---- 5 GCN layers (layer 5 reuses W4/b4, matching the reference) ----
    const int aggGrid  = (N + 7) / 8;    // one node per HALF-WAVE, 8/block
    const int poolGrid = (G + 3) / 4;

    // layer 1
    k_aggregate<<<aggGrid, 256, 0, stream>>>(buf0, indptr, adj, b1, buf1, N);
    // layers 2..5: gemm (+ pool rider of previous h) then aggregate
    const float* bs_[4] = {b2, b3, b4, b4};
    const int Wi_[4] = {1, 2, 3, 3};
    for (int i = 0; i < 4; ++i) {
        k_gemm_pool<<<gemmGrid + poolGrid, 256, 0, stream>>>(
            buf1, Wg + Wi_[i] * 16384, buf0, N, gstart, pbuf, i, G, gemmGrid);
        k_aggregate<<<aggGrid, 256, 0, stream>>>(buf0, indptr, adj, bs_[i], buf1, N);
    }
    k_pool<<<poolGrid, 256, 0, stream>>>(buf1, gstart, pbuf, 4, G);

    // ---- MLP head ----
    dim3 hgrid((G + 63) / 64, 10);   // 640 output cols / 64
    k_head1<<<hgrid, 256, 0, stream>>>(pbuf, Wl1, bl1, zbuf, G);
    k_fc2<<<G, 128, 0, stream>>>(zbuf, Wl2, bl2, out);

    // sentinel: some launch failed synchronously (absmax ~= 48)
    if (hipGetLastError() != hipSuccess)
        hipMemsetAsync(d_out, 0x42, (size_t)out_size * 4, stream);
}

// Round 9
// 608.658 us; speedup vs baseline: 1.4442x; 1.0747x over previous
//
#include <hip/hip_runtime.h>
#include <hip/hip_fp16.h>

#define HID 128   // feature width (D == H == 128)

// ---------------- bf16 helpers ----------------
__device__ __forceinline__ float bf2f(unsigned short u) {
    union { unsigned int i; float f; } v;
    v.i = ((unsigned int)u) << 16;
    return v.f;
}
__device__ __forceinline__ unsigned short f2bf(float f) {
    union { float f; unsigned int i; } v;
    v.f = f;
    unsigned int lsb = (v.i >> 16) & 1u;
    v.i += 0x7fffu + lsb;   // round-to-nearest-even
    return (unsigned short)(v.i >> 16);
}

// ---------------- fp8 e4m3fn helpers ----------------
// t = h@W is stored fp8 (128B/row = one cache line).
template <int S>
__device__ __forceinline__ float fp8_dec(unsigned int v) {
#if __has_builtin(__builtin_amdgcn_cvt_f32_fp8)
    return __builtin_amdgcn_cvt_f32_fp8(v, S);
#else
    unsigned int b = (v >> (S * 8)) & 0xffu;
    unsigned short u = (unsigned short)(((b & 0x80u) << 8) | ((b & 0x7fu) << 7));
    return __half2float(__ushort_as_half(u)) * 256.0f;
#endif
}
// encode: clamp to +-448, f32->f16 (hw RNE), then RNE 10->3 mantissa bits.
__device__ __forceinline__ unsigned char fp8_enc(float f) {
    f = fminf(fmaxf(f, -448.f), 448.f);
    unsigned short u = __half_as_ushort(__float2half(f * 0.00390625f)); // /256
    unsigned short r = (unsigned short)(u + (((u >> 7) & 1u) + 0x3fu));
    return (unsigned char)(((r >> 7) & 0x7fu) | ((u >> 8) & 0x80u));
}

typedef __attribute__((ext_vector_type(8))) short bf16x8;   // 8 bf16 (4 VGPRs)
typedef __attribute__((ext_vector_type(4))) float f32x4;    // MFMA acc

// ---------------- merged preprocessing: deg(+rank) + wprep + gbounds --------
// The degree histogram's atomicAdd return value IS a unique per-edge rank
// within its destination -> stored to rank[] so the fused0 scatter needs NO
// atomics (p = indptr[d] + rank[e]).
__global__ void k_prep(const int* __restrict__ col, int* __restrict__ degI,
                       int* __restrict__ rank,
                       const float* __restrict__ W1, const float* __restrict__ W2,
                       const float* __restrict__ W3, const float* __restrict__ W4,
                       unsigned short* __restrict__ Wg,
                       const int* __restrict__ batch, int* __restrict__ gstart,
                       int E, int N, int G, int degGrid) {
    int bid = blockIdx.x;
    if (bid < degGrid) {                       // ---- degree histogram + rank ----
        int i = bid * 256 + threadIdx.x;
        if (i < E) rank[i] = atomicAdd(&degI[col[i]], 1);
        return;
    }
    bid -= degGrid;
    if (bid < 256) {                           // ---- W pre-swizzle ----
        int m = bid >> 6;                      // matrix index 0..3
        int i = (bid & 63) * 256 + threadIdx.x;
        const float* Wm = (m == 0) ? W1 : (m == 1) ? W2 : (m == 2) ? W3 : W4;
        int k = i >> 7, n = i & 127;
        int ks = k >> 5, q = (k >> 3) & 3, j = k & 7;
        int ct = n >> 4, c = n & 15;
        Wg[m * 16384 + ((((ks * 8 + ct) * 4 + q) * 16 + c) << 3) + j] = f2bf(Wm[i]);
        return;
    }
    bid -= 256;                                // ---- graph bounds ----
    int g = bid * 256 + threadIdx.x;
    if (g > G) return;
    int lo = 0, hi = N;
    while (lo < hi) {
        int mid = (lo + hi) >> 1;
        if (batch[mid] < g) lo = mid + 1; else hi = mid;
    }
    gstart[g] = lo;
}

// ---- 3-phase device-wide exclusive scan of (degI[i]+1) -> indptr ----
__global__ void k_scan_part(const int* __restrict__ degI, int* __restrict__ partial,
                            int* __restrict__ sums, int N) {
    __shared__ int sh[1024];
    int tid = threadIdx.x;
    int i = blockIdx.x * 1024 + tid;
    int v = (i < N) ? (degI[i] + 1) : 0;
    sh[tid] = v;
    __syncthreads();
    for (int off = 1; off < 1024; off <<= 1) {
        int t = (tid >= off) ? sh[tid - off] : 0;
        __syncthreads();
        sh[tid] += t;
        __syncthreads();
    }
    if (i < N) partial[i] = sh[tid] - v;
    if (tid == 1023) sums[blockIdx.x] = sh[1023];
}
__global__ void k_scan_tops(int* __restrict__ sums, int* __restrict__ indptr,
                            int nblocks, int N) {
    __shared__ int sh[1024];
    int tid = threadIdx.x;
    int v = (tid < nblocks) ? sums[tid] : 0;
    sh[tid] = v;
    __syncthreads();
    for (int off = 1; off < 1024; off <<= 1) {
        int t = (tid >= off) ? sh[tid - off] : 0;
        __syncthreads();
        sh[tid] += t;
        __syncthreads();
    }
    if (tid < nblocks) sums[tid] = sh[tid] - v;   // exclusive
    if (tid == 1023) indptr[N] = sh[1023];        // grand total = E + N
}
// phase 3: emit indptr + dinv = 1/sqrt(deg+1)  (no cursor needed anymore)
__global__ void k_scan_fix(const int* __restrict__ partial, const int* __restrict__ sums,
                           const int* __restrict__ degI, int* __restrict__ indptr,
                           float* __restrict__ dinv, int N) {
    int i = blockIdx.x * blockDim.x + threadIdx.x;
    if (i < N) {
        indptr[i] = partial[i] + sums[i >> 10];
        dinv[i] = 1.0f / sqrtf((float)(degI[i] + 1));
    }
}

// ---------------- MFMA GEMM body (C = A @ W, fp8 out) ------------------------
__device__ __forceinline__ bf16x8 a_frag_load(const unsigned short* p) {
    return *(const bf16x8*)p;
}
__device__ __forceinline__ bf16x8 a_frag_load(const float* p) {
    bf16x8 r;
#pragma unroll
    for (int i = 0; i < 8; ++i) r[i] = (short)f2bf(p[i]);
    return r;
}

template <typename TA>
__device__ __forceinline__ void gemm_body(const TA* __restrict__ A,
                                          const unsigned short* __restrict__ B,
                                          unsigned char* __restrict__ C,
                                          int N, int blk) {
    const int tid = threadIdx.x;
    const int lane = tid & 63, wave = tid >> 6;
    const int q = lane >> 4, c = lane & 15;
    const int rowBase = blk * 128 + wave * 32;

    f32x4 acc[2][8];
#pragma unroll
    for (int rt = 0; rt < 2; ++rt)
#pragma unroll
        for (int ct = 0; ct < 8; ++ct)
            acc[rt][ct] = (f32x4){0.f, 0.f, 0.f, 0.f};

    const bf16x8 zfrag = {};
#pragma unroll
    for (int ks = 0; ks < 4; ++ks) {
        bf16x8 a[2];
#pragma unroll
        for (int rt = 0; rt < 2; ++rt) {
            int r = rowBase + rt * 16 + c;
            a[rt] = (r < N) ? a_frag_load(A + (size_t)r * HID + ks * 32 + q * 8)
                            : zfrag;
        }
#pragma unroll
        for (int ct = 0; ct < 8; ++ct) {
            bf16x8 b = *(const bf16x8*)&B[((((ks * 8 + ct) * 4 + q) * 16 + c) << 3)];
            acc[0][ct] = __builtin_amdgcn_mfma_f32_16x16x32_bf16(a[0], b, acc[0][ct], 0, 0, 0);
            acc[1][ct] = __builtin_amdgcn_mfma_f32_16x16x32_bf16(a[1], b, acc[1][ct], 0, 0, 0);
        }
    }
#pragma unroll
    for (int rt = 0; rt < 2; ++rt)
#pragma unroll
        for (int reg = 0; reg < 4; ++reg) {
            int r = rowBase + rt * 16 + q * 4 + reg;
            if (r < N) {
#pragma unroll
                for (int ct = 0; ct < 8; ++ct)
                    C[(size_t)r * HID + ct * 16 + c] = fp8_enc(acc[rt][ct][reg]);
            }
        }
}

// ---------------- mean-pool body (one wave per graph, 8-deep unroll) ---------
__device__ __forceinline__ void pool_body(const unsigned short* __restrict__ h,
                                          const int* __restrict__ gstart,
                                          float* __restrict__ pbuf,
                                          int layer, int g, int lane) {
    int s = gstart[g], e = gstart[g + 1];
    float sx[4] = {0.f, 0.f, 0.f, 0.f};
    float sy[4] = {0.f, 0.f, 0.f, 0.f};
    int v = s;
    for (; v + 7 < e; v += 8) {
        unsigned int pk[8];
#pragma unroll
        for (int u = 0; u < 8; ++u)
            pk[u] = ((const unsigned int*)(h + (size_t)(v + u) * HID))[lane];
#pragma unroll
        for (int u = 0; u < 8; ++u) {
            sx[u & 3] += bf2f((unsigned short)(pk[u] & 0xffffu));
            sy[u & 3] += bf2f((unsigned short)(pk[u] >> 16));
        }
    }
    for (; v < e; ++v) {
        unsigned int pk = ((const unsigned int*)(h + (size_t)v * HID))[lane];
        sx[0] += bf2f((unsigned short)(pk & 0xffffu));
        sy[0] += bf2f((unsigned short)(pk >> 16));
    }
    float inv = 1.0f / fmaxf((float)(e - s), 1.0f);
    float ox = ((sx[0] + sx[1]) + (sx[2] + sx[3])) * inv;
    float oy = ((sy[0] + sy[1]) + (sy[2] + sy[3])) * inv;
    float* dst = pbuf + (size_t)g * 640 + layer * HID + lane * 2;
    dst[0] = ox;
    dst[1] = oy;
}

// fat kernel: layer-0 GEMM (LDS-copied W, fp8 out) + ATOMIC-FREE CSR scatter.
// p = indptr[d] + rank[e] (rank captured during the degree histogram);
// self-loops take the last slot indptr[d+1]-1. Removes 1.7M contended
// cursor atomics from this kernel. adj entries stay 8B int2 (r9 evidence).
__global__ __launch_bounds__(256) void k_fused0(const float* __restrict__ x,
                                                const unsigned short* __restrict__ Wg,
                                                unsigned char* __restrict__ buf0,
                                                const int* __restrict__ row,
                                                const int* __restrict__ col,
                                                const float* __restrict__ dinv,
                                                const int* __restrict__ indptr,
                                                const int* __restrict__ rank,
                                                int2* __restrict__ adj,
                                                int E, int N, int gemmGrid) {
    __shared__ unsigned short Wsw[16384];   // 32 KB (gemm blocks only)
    if (blockIdx.x < gemmGrid) {
        const uint4* src = (const uint4*)Wg;   // straight 16B copy, 0 conflicts
        uint4* dst = (uint4*)Wsw;
        for (int i = threadIdx.x; i < 2048; i += 256) dst[i] = src[i];
        __syncthreads();
        gemm_body<float>(x, Wsw, buf0, N, blockIdx.x);
        return;
    }
    int e = (blockIdx.x - gemmGrid) * blockDim.x + threadIdx.x;
    if (e >= E + N) return;
    int s, d, p;
    if (e < E) { s = row[e]; d = col[e]; p = indptr[d] + rank[e]; }
    else       { s = d = e - E; p = indptr[d + 1] - 1; }   // self loop: last slot
    adj[p] = make_int2(s, __float_as_int(dinv[s] * dinv[d]));
}

// layers 2..5 GEMM (bf16 h in, fp8 t out) + pool rider on h_{L-1} (same
// buffer the GEMM reads -> no race); hides 4 of the 5 pools.
__global__ __launch_bounds__(256) void k_gemm_pool(const unsigned short* __restrict__ A,
                                                   const unsigned short* __restrict__ Wg,
                                                   unsigned char* __restrict__ C,
                                                   int N,
                                                   const int* __restrict__ gstart,
                                                   float* __restrict__ pbuf,
                                                   int poolLayer, int G, int gemmGrid) {
    if (blockIdx.x < gemmGrid) {
        gemm_body<unsigned short>(A, Wg, C, N, blockIdx.x);
        return;
    }
    int g = (blockIdx.x - gemmGrid) * 4 + (threadIdx.x >> 6);
    if (g >= G) return;
    pool_body(A, gstart, pbuf, poolLayer, g, threadIdx.x & 63);
}

// ---------------- CSR gather-aggregate + bias + ReLU (fp8, QUARTER-wave) -----
// r8 proved chain-level parallelism is the aggregate's limiter (half-wave
// split: -14%). Continue the lever: ONE NODE PER QUARTER-WAVE (16 lanes).
// fp8 row = 128B = 16 lanes x 8B (uint2). Each quarter-wave runs its own
// 8-deep unroll -> FOUR independent indptr->adj->gather chains per wave,
// 16 nodes/block, grid 6250 (half the sequential block-rounds of r8).
// Each lane decodes 8 features (VALU/lane doubles; VALU was <=20% -> headroom).
// Tail = ONE masked batch (idx clamped to e-1, weight zeroed; r3-proven).
__global__ __launch_bounds__(256) void k_aggregate(const unsigned char* __restrict__ t,
                                                   const int* __restrict__ indptr,
                                                   const int2* __restrict__ adj,
                                                   const float* __restrict__ bias,
                                                   unsigned short* __restrict__ h, int N) {
    int node = blockIdx.x * 16 + (threadIdx.x >> 4);   // quarter-wave index
    if (node >= N) return;
    int fl = threadIdx.x & 15;         // feature octet: features 8*fl .. 8*fl+7
    int s = indptr[node], e = indptr[node + 1];   // e > s (self-loop)
    const uint2* tu8 = (const uint2*)t;  // 8B = 8 fp8 features

    float a0 = 0.f, a1 = 0.f, a2 = 0.f, a3 = 0.f;
    float a4 = 0.f, a5 = 0.f, a6 = 0.f, a7 = 0.f;

    int p = s;
    for (; p + 7 < e; p += 8) {        // full batches: 8 edges per quarter-wave
        uint2 v[8];
        float w[8];
#pragma unroll
        for (int u = 0; u < 8; ++u) {
            int2 ae = adj[p + u];      // uniform per quarter-wave
            w[u] = __int_as_float(ae.y);
            v[u] = tu8[(size_t)ae.x * 16 + fl];
        }
#pragma unroll
        for (int u = 0; u < 8; ++u) {
            a0 = fmaf(w[u], fp8_dec<0>(v[u].x), a0);
            a1 = fmaf(w[u], fp8_dec<1>(v[u].x), a1);
            a2 = fmaf(w[u], fp8_dec<2>(v[u].x), a2);
            a3 = fmaf(w[u], fp8_dec<3>(v[u].x), a3);
            a4 = fmaf(w[u], fp8_dec<0>(v[u].y), a4);
            a5 = fmaf(w[u], fp8_dec<1>(v[u].y), a5);
            a6 = fmaf(w[u], fp8_dec<2>(v[u].y), a6);
            a7 = fmaf(w[u], fp8_dec<3>(v[u].y), a7);
        }
    }
    if (p < e) {                        // one masked batch covers the tail
        uint2 v[8];
        float w[8];
#pragma unroll
        for (int u = 0; u < 8; ++u) {
            int idx = p + u;
            int2 ae = adj[idx < e ? idx : e - 1];
            w[u] = (idx < e) ? __int_as_float(ae.y) : 0.f;
            v[u] = tu8[(size_t)ae.x * 16 + fl];
        }
#pragma unroll
        for (int u = 0; u < 8; ++u) {
            a0 = fmaf(w[u], fp8_dec<0>(v[u].x), a0);
            a1 = fmaf(w[u], fp8_dec<1>(v[u].x), a1);
            a2 = fmaf(w[u], fp8_dec<2>(v[u].x), a2);
            a3 = fmaf(w[u], fp8_dec<3>(v[u].x), a3);
            a4 = fmaf(w[u], fp8_dec<0>(v[u].y), a4);
            a5 = fmaf(w[u], fp8_dec<1>(v[u].y), a5);
            a6 = fmaf(w[u], fp8_dec<2>(v[u].y), a6);
            a7 = fmaf(w[u], fp8_dec<3>(v[u].y), a7);
        }
    }
    int fb = fl * 8;
    float4 b0 = *(const float4*)(bias + fb);
    float4 b1 = *(const float4*)(bias + fb + 4);
    uint4 pk;
    pk.x = (unsigned int)f2bf(fmaxf(a0 + b0.x, 0.f)) |
           ((unsigned int)f2bf(fmaxf(a1 + b0.y, 0.f)) << 16);
    pk.y = (unsigned int)f2bf(fmaxf(a2 + b0.z, 0.f)) |
           ((unsigned int)f2bf(fmaxf(a3 + b0.w, 0.f)) << 16);
    pk.z = (unsigned int)f2bf(fmaxf(a4 + b1.x, 0.f)) |
           ((unsigned int)f2bf(fmaxf(a5 + b1.y, 0.f)) << 16);
    pk.w = (unsigned int)f2bf(fmaxf(a6 + b1.z, 0.f)) |
           ((unsigned int)f2bf(fmaxf(a7 + b1.w, 0.f)) << 16);
    ((uint4*)(h + (size_t)node * HID))[fl] = pk;   // 16 lanes x 16B = 256B
}

// ---------------- standalone pool (used for the final layer) -----------------
__global__ __launch_bounds__(256) void k_pool(const unsigned short* __restrict__ h,
                                              const int* __restrict__ gstart,
                                              float* __restrict__ pbuf,
                                              int layer, int G) {
    int g = blockIdx.x * 4 + (threadIdx.x >> 6);
    if (g >= G) return;
    pool_body(h, gstart, pbuf, layer, g, threadIdx.x & 63);
}

// ---------------- MLP head: Z[G,640] = relu(P[G,640] @ Wl1 + bl1) ------------
__global__ __launch_bounds__(256) void k_head1(const float* __restrict__ P,
                                               const float* __restrict__ Wl1,
                                               const float* __restrict__ bl1,
                                               float* __restrict__ Z, int G) {
    __shared__ float As[64][68];
    __shared__ float Ws[64][64];
    const int tid = threadIdx.x;
    const int tr = tid >> 4;
    const int tc = tid & 15;
    const int gBase = blockIdx.x * 64;
    const int cBase = blockIdx.y * 64;

    float acc[4][4];
#pragma unroll
    for (int i = 0; i < 4; ++i)
#pragma unroll
        for (int j = 0; j < 4; ++j) acc[i][j] = 0.f;

    for (int kb = 0; kb < 640; kb += 64) {
#pragma unroll
        for (int i = 0; i < 4; ++i) {
            int f4 = tid + i * 256;
            int r  = f4 >> 4;
            int kc = (f4 & 15) << 2;
            int gg = gBase + r;
            float4 v = {0.f, 0.f, 0.f, 0.f};
            if (gg < G) v = *(const float4*)(P + (size_t)gg * 640 + kb + kc);
            As[kc + 0][r] = v.x; As[kc + 1][r] = v.y;
            As[kc + 2][r] = v.z; As[kc + 3][r] = v.w;
        }
#pragma unroll
        for (int i = 0; i < 4; ++i) {
            int f4 = tid + i * 256;
            int k  = f4 >> 4;
            int c4 = (f4 & 15) << 2;
            *(float4*)&Ws[k][c4] =
                *(const float4*)(Wl1 + (size_t)(kb + k) * 640 + cBase + c4);
        }
        __syncthreads();
#pragma unroll
        for (int k = 0; k < 64; ++k) {
            float a[4], w[4];
            *(float4*)&a[0] = *(const float4*)&As[k][tr * 4];
            *(float4*)&w[0] = *(const float4*)&Ws[k][tc * 4];
#pragma unroll
            for (int i = 0; i < 4; ++i)
#pragma unroll
                for (int j = 0; j < 4; ++j)
                    acc[i][j] = fmaf(a[i], w[j], acc[i][j]);
        }
        __syncthreads();
    }
#pragma unroll
    for (int i = 0; i < 4; ++i) {
        int gg = gBase + tr * 4 + i;
        if (gg < G) {
            float4 o;
            o.x = fmaxf(acc[i][0] + bl1[cBase + tc * 4 + 0], 0.f);
            o.y = fmaxf(acc[i][1] + bl1[cBase + tc * 4 + 1], 0.f);
            o.z = fmaxf(acc[i][2] + bl1[cBase + tc * 4 + 2], 0.f);
            o.w = fmaxf(acc[i][3] + bl1[cBase + tc * 4 + 3], 0.f);
            *(float4*)(Z + (size_t)gg * 640 + cBase + tc * 4) = o;
        }
    }
}

__global__ void k_fc2(const float* __restrict__ zbuf, const float* __restrict__ Wl2,
                      const float* __restrict__ bl2, float* __restrict__ out) {
    int g = blockIdx.x;
    int t = threadIdx.x;  // 128 threads = 2 waves
    float s = 0.f;
    for (int k = t; k < 640; k += 128) s = fmaf(zbuf[(size_t)g * 640 + k], Wl2[k], s);
#pragma unroll
    for (int off = 32; off > 0; off >>= 1) s += __shfl_down(s, off);
    __shared__ float ws[2];
    if ((t & 63) == 0) ws[t >> 6] = s;
    __syncthreads();
    if (t == 0) out[g] = ws[0] + ws[1] + bl2[0];
}

// ---------------- driver ----------------
extern "C" void kernel_launch(void* const* d_in, const int* in_sizes, int n_in,
                              void* d_out, int out_size, void* d_ws, size_t ws_size,
                              hipStream_t stream) {
    const float* x    = (const float*)d_in[0];
    const int*   edge = (const int*)d_in[1];
    const int*   bat  = (const int*)d_in[2];
    const float* W1   = (const float*)d_in[3];
    const float* b1   = (const float*)d_in[4];
    const float* W2   = (const float*)d_in[5];
    const float* b2   = (const float*)d_in[6];
    const float* W3   = (const float*)d_in[7];
    const float* b3   = (const float*)d_in[8];
    const float* W4   = (const float*)d_in[9];
    const float* b4   = (const float*)d_in[10];
    const float* Wl1  = (const float*)d_in[11];
    const float* bl1  = (const float*)d_in[12];
    const float* Wl2  = (const float*)d_in[13];
    const float* bl2  = (const float*)d_in[14];
    float*       out  = (float*)d_out;

    const int N = in_sizes[2];       // 100000
    const int E = in_sizes[1] / 2;   // 1600000
    const int G = out_size;          // 512
    (void)n_in; (void)ws_size;

    (void)hipGetLastError();  // clear any stale error

    // ---- workspace carve ----
    size_t off = 0;
    auto alloc = [&](size_t bytes) -> void* {
        void* p = (void*)((char*)d_ws + off);
        off += (bytes + 255) & ~(size_t)255;
        return p;
    };
    unsigned char*  buf0 = (unsigned char*)alloc((size_t)N * HID);       // t, fp8
    unsigned short* buf1 = (unsigned short*)alloc((size_t)N * HID * 2);  // h, bf16
    unsigned short* Wg   = (unsigned short*)alloc((size_t)4 * 16384 * 2); // swizzled W1..4
    float* dinv   = (float*)alloc((size_t)N * 4);
    int*   degI   = (int*)alloc((size_t)N * 4);
    int*   rank   = (int*)alloc((size_t)E * 4);
    int*   indptr = (int*)alloc((size_t)(N + 1) * 4);
    int*   partial= (int*)alloc((size_t)N * 4);
    int*   bsums  = (int*)alloc((size_t)1024 * 4);
    int2*  adj    = (int2*)alloc((size_t)(E + N) * 8);
    int*   gstart = (int*)alloc((size_t)(G + 1) * 4);
    float* pbuf   = (float*)alloc((size_t)G * 640 * 4);
    float* zbuf   = (float*)alloc((size_t)G * 640 * 4);

    const int* rowv = edge;      // sources
    const int* colv = edge + E;  // destinations

    // ---- preprocessing (merged; rank captured during histogram) ----
    hipMemsetAsync(degI, 0, (size_t)N * 4, stream);
    const int degGrid = (E + 255) / 256;
    const int gbGrid  = (G + 256) / 256;
    k_prep<<<degGrid + 256 + gbGrid, 256, 0, stream>>>(colv, degI, rank,
                                                       W1, W2, W3, W4, Wg,
                                                       bat, gstart,
                                                       E, N, G, degGrid);
    const int scanBlocks = (N + 1023) / 1024;
    k_scan_part<<<scanBlocks, 1024, 0, stream>>>(degI, partial, bsums, N);
    k_scan_tops<<<1, 1024, 0, stream>>>(bsums, indptr, scanBlocks, N);
    k_scan_fix<<<(N + 255) / 256, 256, 0, stream>>>(partial, bsums, degI,
                                                    indptr, dinv, N);

    // ---- fused: layer-0 GEMM (LDS W, fp8 out) + atomic-free scatter ----
    const int gemmGrid = (N + 127) / 128;
    const int scatGrid = (E + N + 255) / 256;
    k_fused0<<<gemmGrid + scatGrid, 256, 0, stream>>>(x, Wg, buf0, rowv, colv,
                                                      dinv, indptr, rank, adj,
                                                      E, N, gemmGrid);

    // ---- 5 GCN layers (layer 5 reuses W4/b4, matching the reference) ----
    const int aggGrid  = (N + 15) / 16;  // one node per QUARTER-WAVE, 16/block
    const int poolGrid = (G + 3) / 4;

    // layer 1
    k_aggregate<<<aggGrid, 256, 0, stream>>>(buf0, indptr, adj, b1, buf1, N);
    // layers 2..5: gemm (+ pool rider of previous h) then aggregate
    const float* bs_[4] = {b2, b3, b4, b4};
    const int Wi_[4] = {1, 2, 3, 3};
    for (int i = 0; i < 4; ++i) {
        k_gemm_pool<<<gemmGrid + poolGrid, 256, 0, stream>>>(
            buf1, Wg + Wi_[i] * 16384, buf0, N, gstart, pbuf, i, G, gemmGrid);
        k_aggregate<<<aggGrid, 256, 0, stream>>>(buf0, indptr, adj, bs_[i], buf1, N);
    }
    k_pool<<<poolGrid, 256, 0, stream>>>(buf1, gstart, pbuf, 4, G);

    // ---- MLP head ----
    dim3 hgrid((G + 63) / 64, 10);   // 640 output cols / 64
    k_head1<<<hgrid, 256, 0, stream>>>(pbuf, Wl1, bl1, zbuf, G);
    k_fc2<<<G, 128, 0, stream>>>(zbuf, Wl2, bl2, out);

    // sentinel: some launch failed synchronously (absmax ~= 48)
    if (hipGetLastError() != hipSuccess)
        hipMemsetAsync(d_out, 0x42, (size_t)out_size * 4, stream);
}